// Round 1
// 547.994 us; speedup vs baseline: 1.0440x; 1.0440x over previous
//
#include <hip/hip_runtime.h>
#include <math.h>

#define B_  4
#define S_  2048
#define D_  1024
#define H_  16
#define HD_ 64
#define DF_ 4096
#define M_  (B_*S_)   // 8192 rows

typedef unsigned short ushort_t;
typedef __bf16 bf16x8 __attribute__((ext_vector_type(8)));
typedef float  f32x4  __attribute__((ext_vector_type(4)));
typedef unsigned u32x4 __attribute__((ext_vector_type(4)));

#define FA_SCALE 0.18033688011112042f  // (1/8) * log2(e)

__device__ __forceinline__ ushort_t f2bf(float f) {
  union { float f; unsigned u; } v; v.f = f;
  unsigned r = v.u + 0x7FFFu + ((v.u >> 16) & 1u);
  return (ushort_t)(r >> 16);
}

__device__ __forceinline__ float bf2f(ushort_t u) {
  union { unsigned u; float f; } v; v.u = ((unsigned)u) << 16; return v.f;
}

// round-half-up bf16 pack of two floats -> u32 (lo = a, hi = b), 3 VALU ops
__device__ __forceinline__ unsigned pack_bf2(float a, float b) {
  union { float f; unsigned u; } ua, ub; ua.f = a; ub.f = b;
  return __builtin_amdgcn_perm(ub.u + 0x8000u, ua.u + 0x8000u, 0x07060302u);
}

__device__ __forceinline__ float fexp2(float x) {
#if __has_builtin(__builtin_amdgcn_exp2f)
  return __builtin_amdgcn_exp2f(x);
#else
  return __expf(x * 0.6931471805599453f);
#endif
}

// tanh-form GELU via exp2+rcp: ~5 VALU ops
__device__ __forceinline__ float fgelu(float x) {
  float e = fexp2(x * fmaf(x * x, -0.10295358f, -2.30221510f));
  return x * __builtin_amdgcn_rcpf(1.0f + e);
}

__device__ __forceinline__ void gload16(const void* g, void* l) {
  __builtin_amdgcn_global_load_lds(
      (const __attribute__((address_space(1))) void*)g,
      (__attribute__((address_space(3))) void*)l, 16, 0, 0);
}

#define PBAR() do { asm volatile("" ::: "memory"); \
                    __builtin_amdgcn_s_barrier();  \
                    asm volatile("" ::: "memory"); } while (0)

// ---------------- fp32 [R][C] -> bf16 [C][R] transpose+convert ----------------
__global__ __launch_bounds__(256) void transpose_cvt(
    const float* __restrict__ in, ushort_t* __restrict__ out, int R, int C) {
  __shared__ float tile[32][33];
  int tx = threadIdx.x & 31, ty = threadIdx.x >> 5;
  int r0 = blockIdx.y * 32, c0 = blockIdx.x * 32;
  #pragma unroll
  for (int i = 0; i < 32; i += 8)
    tile[ty + i][tx] = in[(size_t)(r0 + ty + i) * C + c0 + tx];
  __syncthreads();
  #pragma unroll
  for (int i = 0; i < 32; i += 8)
    out[(size_t)(c0 + ty + i) * R + r0 + tx] = f2bf(tile[tx][ty + i]);
}

struct TP4 { const float* src[4]; ushort_t* dst[4]; };
__global__ __launch_bounds__(256) void transpose_cvt4(TP4 p) {
  __shared__ float tile[32][33];
  const float* in = p.src[blockIdx.z];
  ushort_t* out = p.dst[blockIdx.z];
  int tx = threadIdx.x & 31, ty = threadIdx.x >> 5;
  int r0 = blockIdx.y * 32, c0 = blockIdx.x * 32;
  #pragma unroll
  for (int i = 0; i < 32; i += 8)
    tile[ty + i][tx] = in[(size_t)(r0 + ty + i) * D_ + c0 + tx];
  __syncthreads();
  #pragma unroll
  for (int i = 0; i < 32; i += 8)
    out[(size_t)(c0 + ty + i) * D_ + r0 + tx] = f2bf(tile[tx][ty + i]);
}

// ---------------- layernorm row(1024) -> bf16 (fp32 or bf16 input) ----------------
template <int BF_IN>
__global__ __launch_bounds__(256) void ln_kernel(
    const void* __restrict__ xv, const float* __restrict__ g,
    const float* __restrict__ b, ushort_t* __restrict__ out) {
  int row = blockIdx.x;
  int t = threadIdx.x;
  float4 v;
  if constexpr (BF_IN) {
    ushort4 raw = ((const ushort4*)((const ushort_t*)xv + (size_t)row * D_))[t];
    v.x = bf2f(raw.x); v.y = bf2f(raw.y); v.z = bf2f(raw.z); v.w = bf2f(raw.w);
  } else {
    v = ((const float4*)((const float*)xv + (size_t)row * D_))[t];
  }
  float s  = v.x + v.y + v.z + v.w;
  float ss = v.x*v.x + v.y*v.y + v.z*v.z + v.w*v.w;
  #pragma unroll
  for (int off = 32; off > 0; off >>= 1) {
    s  += __shfl_down(s, off);
    ss += __shfl_down(ss, off);
  }
  __shared__ float sh[8];
  int w = t >> 6, lane = t & 63;
  if (lane == 0) { sh[w] = s; sh[4 + w] = ss; }
  __syncthreads();
  if (t == 0) {
    float a  = sh[0] + sh[1] + sh[2] + sh[3];
    float a2 = sh[4] + sh[5] + sh[6] + sh[7];
    float mean = a * (1.0f / D_);
    float var  = a2 * (1.0f / D_) - mean * mean;
    sh[0] = mean; sh[1] = rsqrtf(var + 1e-5f);
  }
  __syncthreads();
  float mean = sh[0], rstd = sh[1];
  float4 gv = ((const float4*)g)[t];
  float4 bv = ((const float4*)b)[t];
  ushort4 o;
  o.x = f2bf((v.x - mean) * rstd * gv.x + bv.x);
  o.y = f2bf((v.y - mean) * rstd * gv.y + bv.y);
  o.z = f2bf((v.z - mean) * rstd * gv.z + bv.z);
  o.w = f2bf((v.w - mean) * rstd * gv.w + bv.w);
  ((ushort4*)(out + (size_t)row * D_))[t] = o;
}

// ---------------- GEMM 256x256, BK=64, 8 waves, phase-pipelined ----------------
// C[M,N] = A[M,K](bf16) @ BT[N,K](bf16)^T + bias. Accumulator TRANSPOSED
// (swapped MFMA operands): reg r -> n (4 consecutive), lane l16 -> m.
// Schedule per K-tile U (4 phases, 16 MFMA each, one barrier per phase):
//   P1: ldB(nh0)+ldA(mh0) | stage A_half0(U+1)->buf^1 | MFMA Q(0,0)
//   P2: ldB(nh1)          | stage A_half1(U+1)->buf^1 | MFMA Q(0,1)
//   P3: ldA(mh1)          | stage B_half0(U+2)->buf   | MFMA Q(1,1)
//   P4: (no reads)        | stage B_half1(U+2)->buf   | MFMA Q(1,0)
// Boundary: s_waitcnt vmcnt(4) (2 half-tiles stay in flight), vmcnt(0) only at
// the last tile. B region of the CURRENT buffer is overwritten at P3/P4 (its
// last readers finished before P2's end barrier); A goes to the other buffer.
// LDS XOR-swizzle: LDS[r][c] = global[r][c ^ (r&7)] (chunk = 8 bf16), achieved
// by pre-swizzling the per-lane global source (LDS dest stays linear), and
// reading chunk (kchunk ^ (r&7)) -> 2-way max on ds_read_b128 (free).
// MODE 2: attn out proj: bf16 o0 = resF(f32) + acc + bias
// MODE 3: FFN1: bf16 o0 = fast_gelu(acc + bias)
// MODE 4: FFN2: f32 outF = resB(bf16) + acc + bias
// MODE 5: fused QKV: kind = n0>>10: 0->Q (pre-scaled), 1->K, 2->V([BH][HD][S])
template <int MODE>
__global__ __launch_bounds__(512, 2) void gemm256(
    const ushort_t* __restrict__ A, const ushort_t* __restrict__ BT,
    const float* __restrict__ b0, const float* __restrict__ b1,
    const float* __restrict__ b2, const float* __restrict__ resF,
    const ushort_t* __restrict__ resB,
    float* __restrict__ outF, ushort_t* __restrict__ o0,
    ushort_t* __restrict__ o1, ushort_t* __restrict__ o2,
    int M, int N, int K) {
  __shared__ __align__(16) ushort_t lds[2][2][256 * 64];  // [buf][A/B][row*64+chunk*8]
  const int t = threadIdx.x;
  const int lane = t & 63, w = t >> 6;
  const int wy = w >> 2, wx = w & 3;
  const int q8 = lane >> 4, l16 = lane & 15;
  const int c7 = l16 & 7;

  // XCD-chunked swizzle: dispatch-slot d -> logical tile (d%8)*cpx + d/8
  // (blocks sharing an A-panel are logical-consecutive -> same XCD L2)
  const int nX = gridDim.x;
  const int lin = blockIdx.y * nX + blockIdx.x;
  const int cpx = (nX * gridDim.y) >> 3;   // nwg % 8 == 0 for all call sites
  const int L = (lin & 7) * cpx + (lin >> 3);
  const int n0 = (L % nX) * 256;
  const int m0 = (L / nX) * 256;

  // staging: lane covers row (w*8 + lane>>3) (+64*i), global chunk pre-swizzled
  const int srow = lane >> 3;
  const int schk = (lane & 7) ^ srow;
  const ushort_t* Ab = A  + (size_t)(m0 + w * 8 + srow) * K + schk * 8;
  const ushort_t* Bb = BT + (size_t)(n0 + w * 8 + srow) * K + schk * 8;

  auto stageA = [&](int k0, int buf, int half) {
    #pragma unroll
    for (int i = half * 2; i < half * 2 + 2; ++i)
      gload16(Ab + (size_t)(i * 64) * K + k0, &lds[buf][0][(i * 64 + w * 8) * 64]);
  };
  auto stageB = [&](int k0, int buf, int half) {
    #pragma unroll
    for (int i = half * 2; i < half * 2 + 2; ++i)
      gload16(Bb + (size_t)(i * 64) * K + k0, &lds[buf][1][(i * 64 + w * 8) * 64]);
  };

  auto ldA = [&](int buf, int mh, bf16x8 (&A4)[4][2]) {
    #pragma unroll
    for (int mi = 0; mi < 4; ++mi) {
      const ushort_t* p = &lds[buf][0][(wy * 128 + mh * 64 + mi * 16 + l16) * 64];
      A4[mi][0] = *(const bf16x8*)(p + ((q8 ^ c7) << 3));
      A4[mi][1] = *(const bf16x8*)(p + (((4 + q8) ^ c7) << 3));
    }
  };
  auto ldB = [&](int buf, int nh, bf16x8 (&B2)[2][2]) {
    #pragma unroll
    for (int ni = 0; ni < 2; ++ni) {
      const ushort_t* p = &lds[buf][1][(wx * 64 + nh * 32 + ni * 16 + l16) * 64];
      B2[ni][0] = *(const bf16x8*)(p + ((q8 ^ c7) << 3));
      B2[ni][1] = *(const bf16x8*)(p + (((4 + q8) ^ c7) << 3));
    }
  };

  f32x4 acc[8][4] = {};
  auto mfmaQ = [&](int mh, int nh, bf16x8 (&A4)[4][2], bf16x8 (&B2)[2][2]) {
    #pragma unroll
    for (int mi = 0; mi < 4; ++mi)
      #pragma unroll
      for (int ni = 0; ni < 2; ++ni) {
        f32x4 c = acc[mh * 4 + mi][nh * 2 + ni];
        c = __builtin_amdgcn_mfma_f32_16x16x32_bf16(B2[ni][0], A4[mi][0], c, 0, 0, 0);
        c = __builtin_amdgcn_mfma_f32_16x16x32_bf16(B2[ni][1], A4[mi][1], c, 0, 0, 0);
        acc[mh * 4 + mi][nh * 2 + ni] = c;
      }
  };

  const int nT = K >> 6;
  // prologue: A(0),B(0) -> buf0 ; B(1) -> buf1. At first boundary the newest
  // 4 loads are B(1) -> vmcnt(4) leaves exactly those in flight.
  stageA(0, 0, 0); stageA(0, 0, 1);
  stageB(0, 0, 0); stageB(0, 0, 1);
  if (nT > 1) { stageB(64, 1, 0); stageB(64, 1, 1); }

  bf16x8 bA[4][2];
  bf16x8 bB[2][2][2];  // [nh][ni][kk]

  for (int U = 0; U < nT; ++U) {
    const int buf = U & 1;
    // boundary: everything older than the newest 2 half-tiles has landed
    if (U == nT - 1) asm volatile("s_waitcnt vmcnt(0)" ::: "memory");
    else             asm volatile("s_waitcnt vmcnt(4)" ::: "memory");
    __builtin_amdgcn_s_barrier();
    asm volatile("" ::: "memory");
    // ---- P1: Q(0,0)
    ldB(buf, 0, bB[0]);
    ldA(buf, 0, bA);
    if (U + 1 < nT) stageA((U + 1) << 6, buf ^ 1, 0);
    __builtin_amdgcn_s_setprio(1);
    mfmaQ(0, 0, bA, bB[0]);
    __builtin_amdgcn_s_setprio(0);
    PBAR();
    // ---- P2: Q(0,1)
    ldB(buf, 1, bB[1]);
    if (U + 1 < nT) stageA((U + 1) << 6, buf ^ 1, 1);
    __builtin_amdgcn_s_setprio(1);
    mfmaQ(0, 1, bA, bB[1]);
    __builtin_amdgcn_s_setprio(0);
    PBAR();
    // ---- P3: Q(1,1)  (B(U) fully read at P1/P2 -> safe to restage B region)
    ldA(buf, 1, bA);
    if (U + 2 < nT) stageB((U + 2) << 6, buf, 0);
    __builtin_amdgcn_s_setprio(1);
    mfmaQ(1, 1, bA, bB[1]);
    __builtin_amdgcn_s_setprio(0);
    PBAR();
    // ---- P4: Q(1,0)  (no ds_reads; boundary vmcnt+barrier at loop top)
    if (U + 2 < nT) stageB((U + 2) << 6, buf, 1);
    __builtin_amdgcn_s_setprio(1);
    mfmaQ(1, 0, bA, bB[0]);
    __builtin_amdgcn_s_setprio(0);
  }

  // ---------------- epilogues (acc layout: reg r -> n, l16 -> m) ----------------
  if constexpr (MODE == 5) {
    const int kind = n0 >> 10;                       // block-uniform (256 | 1024)
    const float* bp = (kind == 0) ? b0 : (kind == 1) ? b1 : b2;
    ushort_t* dst = (kind == 0) ? o0 : (kind == 1) ? o1 : o2;
    #pragma unroll
    for (int ni = 0; ni < 4; ++ni) {
      int nn = (n0 & 1023) + wx * 64 + ni * 16 + q8 * 4;
      int h = nn >> 6, hd = nn & 63;
      float4 bb = *(const float4*)(bp + nn);
      #pragma unroll
      for (int mi = 0; mi < 8; ++mi) {
        int m = m0 + wy * 128 + mi * 16 + l16;
        int b = m >> 11, s = m & (S_ - 1);
        f32x4 a = acc[mi][ni];
        float v0 = a[0] + bb.x, v1 = a[1] + bb.y, v2 = a[2] + bb.z, v3 = a[3] + bb.w;
        if (kind == 0) { v0 *= FA_SCALE; v1 *= FA_SCALE; v2 *= FA_SCALE; v3 *= FA_SCALE; }
        if (kind == 2) {
          size_t base = ((size_t)(b * H_ + h) * HD_ + hd) * S_ + s;
          dst[base]          = f2bf(v0);
          dst[base + S_]     = f2bf(v1);
          dst[base + 2 * S_] = f2bf(v2);
          dst[base + 3 * S_] = f2bf(v3);
        } else {
          uint2 pk;
          pk.x = pack_bf2(v0, v1);
          pk.y = pack_bf2(v2, v3);
          *(uint2*)(dst + ((size_t)(b * H_ + h) * S_ + s) * HD_ + hd) = pk;
        }
      }
    }
  } else {
    #pragma unroll
    for (int ni = 0; ni < 4; ++ni) {
      int n = n0 + wx * 64 + ni * 16 + q8 * 4;
      float4 bb = *(const float4*)(b0 + n);
      #pragma unroll
      for (int mi = 0; mi < 8; ++mi) {
        int m = m0 + wy * 128 + mi * 16 + l16;
        size_t idx = (size_t)m * N + n;
        f32x4 a = acc[mi][ni];
        if constexpr (MODE == 2) {
          float4 r4 = *(const float4*)(resF + idx);
          uint2 pk;
          pk.x = pack_bf2(r4.x + a[0] + bb.x, r4.y + a[1] + bb.y);
          pk.y = pack_bf2(r4.z + a[2] + bb.z, r4.w + a[3] + bb.w);
          *(uint2*)(o0 + idx) = pk;
        } else if constexpr (MODE == 4) {
          ushort4 r4 = *(const ushort4*)(resB + idx);
          float4 o4;
          o4.x = bf2f(r4.x) + a[0] + bb.x;
          o4.y = bf2f(r4.y) + a[1] + bb.y;
          o4.z = bf2f(r4.z) + a[2] + bb.z;
          o4.w = bf2f(r4.w) + a[3] + bb.w;
          *(float4*)(outF + idx) = o4;
        } else {  // MODE 3
          uint2 pk;
          pk.x = pack_bf2(fgelu(a[0] + bb.x), fgelu(a[1] + bb.y));
          pk.y = pack_bf2(fgelu(a[2] + bb.z), fgelu(a[3] + bb.w));
          *(uint2*)(o0 + idx) = pk;
        }
      }
    }
  }
}

// ---------------- flash attention v4 (register-resident P, 32 KB LDS) ----------------
// Qt (pre-scaled), Kt: bf16 [BH][S][HD]; Vt: bf16 [BH][HD][S]; Ao: bf16 [B,S,H,HD]
__global__ __launch_bounds__(256) void flash_attn(
    const ushort_t* __restrict__ Qt, const ushort_t* __restrict__ Kt,
    const ushort_t* __restrict__ Vt, ushort_t* __restrict__ Ao) {
  __shared__ __align__(16) ushort_t ks[2][64 * 64];
  __shared__ __align__(16) ushort_t vs[2][64 * 64];
  const int t = threadIdx.x;
  const int lane = t & 63, w = t >> 6;
  const int q8 = lane >> 4, l16 = lane & 15;
  const int bh = blockIdx.x, q0 = blockIdx.y * 128;
  const int c7 = l16 & 7;
  const int koff0 = ((q8)     ^ c7) * 8;
  const int koff1 = ((4 + q8) ^ c7) * 8;
  const int half4 = (q8 & 1) * 4;
  const int voff00 = (((q8 >> 1)    ) ^ c7) * 8 + half4;
  const int voff01 = (((q8 >> 1) + 2) ^ c7) * 8 + half4;
  const int voff10 = (((q8 >> 1) + 4) ^ c7) * 8 + half4;
  const int voff11 = (((q8 >> 1) + 6) ^ c7) * 8 + half4;

  bf16x8 bq[2][2];
  #pragma unroll
  for (int u = 0; u < 2; ++u)
    #pragma unroll
    for (int kc = 0; kc < 2; ++kc) {
      int row = q0 + w * 32 + u * 16 + l16;
      bq[u][kc] = *(const bf16x8*)(Qt + ((size_t)bh * S_ + row) * HD_ + kc * 32 + q8 * 8);
    }

  const ushort_t* Kg = Kt + (size_t)bh * S_ * HD_;
  const ushort_t* Vg = Vt + (size_t)bh * HD_ * S_;

  #pragma unroll
  for (int i = 0; i < 2; ++i) {
    int slot = i * 256 + t;
    int row = slot >> 3, gch = (slot & 7) ^ (row & 7);
    gload16(Kg + row * HD_ + gch * 8,        ks[0] + (i * 256 + w * 64) * 8);
    gload16(Vg + (size_t)row * S_ + gch * 8, vs[0] + (i * 256 + w * 64) * 8);
  }

  bf16x8 kone;
  #pragma unroll
  for (int i = 0; i < 8; ++i) kone[i] = (__bf16)1.0f;

  f32x4 accO[2][4] = {};
  f32x4 accL[2] = {};

  for (int it = 0; it < S_ / 64; ++it) {
    __syncthreads();
    const int cur = it & 1;
    if (it + 1 < S_ / 64) {
      const ushort_t* Kn = Kg + (size_t)(it + 1) * 64 * HD_;
      const ushort_t* Vn = Vg + (it + 1) * 64;
      #pragma unroll
      for (int i = 0; i < 2; ++i) {
        int slot = i * 256 + t;
        int row = slot >> 3, gch = (slot & 7) ^ (row & 7);
        gload16(Kn + row * HD_ + gch * 8,        ks[cur ^ 1] + (i * 256 + w * 64) * 8);
        gload16(Vn + (size_t)row * S_ + gch * 8, vs[cur ^ 1] + (i * 256 + w * 64) * 8);
      }
    }
    const ushort_t* kbuf = ks[cur];
    const ushort_t* vbuf = vs[cur];

    f32x4 st[2][4];
    #pragma unroll
    for (int ni = 0; ni < 4; ++ni) {
      const ushort_t* kr = kbuf + (ni * 16 + l16) * 64;
      bf16x8 ak0 = *(const bf16x8*)(kr + koff0);
      bf16x8 ak1 = *(const bf16x8*)(kr + koff1);
      #pragma unroll
      for (int u = 0; u < 2; ++u) {
        f32x4 z = {0.f, 0.f, 0.f, 0.f};
        z = __builtin_amdgcn_mfma_f32_16x16x32_bf16(ak0, bq[u][0], z, 0, 0, 0);
        z = __builtin_amdgcn_mfma_f32_16x16x32_bf16(ak1, bq[u][1], z, 0, 0, 0);
        st[u][ni] = z;
      }
    }
    bf16x8 bp[2][2];
    #pragma unroll
    for (int u = 0; u < 2; ++u) {
      uint2 pk[4];
      #pragma unroll
      for (int ni = 0; ni < 4; ++ni) {
        pk[ni].x = pack_bf2(fexp2(st[u][ni][0]), fexp2(st[u][ni][1]));
        pk[ni].y = pack_bf2(fexp2(st[u][ni][2]), fexp2(st[u][ni][3]));
      }
      u32x4 d0 = {pk[0].x, pk[0].y, pk[1].x, pk[1].y};
      u32x4 d1 = {pk[2].x, pk[2].y, pk[3].x, pk[3].y};
      bp[u][0] = __builtin_bit_cast(bf16x8, d0);
      bp[u][1] = __builtin_bit_cast(bf16x8, d1);
    }
    #pragma unroll
    for (int u = 0; u < 2; ++u) {
      accL[u] = __builtin_amdgcn_mfma_f32_16x16x32_bf16(kone, bp[u][0], accL[u], 0, 0, 0);
      accL[u] = __builtin_amdgcn_mfma_f32_16x16x32_bf16(kone, bp[u][1], accL[u], 0, 0, 0);
    }
    #pragma unroll
    for (int ni = 0; ni < 4; ++ni) {
      const ushort_t* vr = vbuf + (ni * 16 + l16) * 64;
      uint2 lo0 = *(const uint2*)(vr + voff00);
      uint2 hi0 = *(const uint2*)(vr + voff01);
      uint2 lo1 = *(const uint2*)(vr + voff10);
      uint2 hi1 = *(const uint2*)(vr + voff11);
      u32x4 a0 = {lo0.x, lo0.y, hi0.x, hi0.y};
      u32x4 a1 = {lo1.x, lo1.y, hi1.x, hi1.y};
      bf16x8 av0 = __builtin_bit_cast(bf16x8, a0);
      bf16x8 av1 = __builtin_bit_cast(bf16x8, a1);
      #pragma unroll
      for (int u = 0; u < 2; ++u) {
        accO[u][ni] = __builtin_amdgcn_mfma_f32_16x16x32_bf16(av0, bp[u][0], accO[u][ni], 0, 0, 0);
        accO[u][ni] = __builtin_amdgcn_mfma_f32_16x16x32_bf16(av1, bp[u][1], accO[u][ni], 0, 0, 0);
      }
    }
  }

  const int b = bh >> 4, h = bh & 15;
  #pragma unroll
  for (int u = 0; u < 2; ++u) {
    float inv = 1.0f / accL[u][0];
    int q = q0 + w * 32 + u * 16 + l16;
    #pragma unroll
    for (int ni = 0; ni < 4; ++ni) {
      uint2 pk;
      pk.x = pack_bf2(accO[u][ni][0] * inv, accO[u][ni][1] * inv);
      pk.y = pack_bf2(accO[u][ni][2] * inv, accO[u][ni][3] * inv);
      *(uint2*)(Ao + (((size_t)b * S_ + q) * H_ + h) * HD_ + ni * 16 + q8 * 4) = pk;
    }
  }
}

extern "C" void kernel_launch(void* const* d_in, const int* in_sizes, int n_in,
                              void* d_out, int out_size, void* d_ws, size_t ws_size,
                              hipStream_t stream) {
  const float* x    = (const float*)d_in[0];
  const float* Wq   = (const float*)d_in[1];
  const float* bq   = (const float*)d_in[2];
  const float* Wk   = (const float*)d_in[3];
  const float* bk   = (const float*)d_in[4];
  const float* Wv   = (const float*)d_in[5];
  const float* bv   = (const float*)d_in[6];
  const float* Wo   = (const float*)d_in[7];
  const float* bo   = (const float*)d_in[8];
  const float* ln1g = (const float*)d_in[9];
  const float* ln1b = (const float*)d_in[10];
  const float* ln2g = (const float*)d_in[11];
  const float* ln2b = (const float*)d_in[12];
  const float* W1   = (const float*)d_in[13];
  const float* b1   = (const float*)d_in[14];
  const float* W2   = (const float*)d_in[15];
  const float* b2   = (const float*)d_in[16];
  float* out = (float*)d_out;

  char* ws = (char*)d_ws;
  ushort_t* WqT = (ushort_t*)(ws + (size_t)(0)  * (1 << 20));  // 2 MB  } contiguous
  ushort_t* WkT = (ushort_t*)(ws + (size_t)(2)  * (1 << 20));  // 2 MB  } [3072][1024]
  ushort_t* WvT = (ushort_t*)(ws + (size_t)(4)  * (1 << 20));  // 2 MB  } fused QKV
  ushort_t* WoT = (ushort_t*)(ws + (size_t)(6)  * (1 << 20));  // 2 MB
  ushort_t* W1T = (ushort_t*)(ws + (size_t)(8)  * (1 << 20));  // 8 MB  [DF][D]
  ushort_t* W2T = (ushort_t*)(ws + (size_t)(16) * (1 << 20));  // 8 MB  [D][DF]
  ushort_t* xn  = (ushort_t*)(ws + (size_t)(24) * (1 << 20));  // 16 MB [M][D]
  ushort_t* qT  = (ushort_t*)(ws + (size_t)(40) * (1 << 20));  // 16 MB [BH][S][HD]
  ushort_t* kT  = (ushort_t*)(ws + (size_t)(56) * (1 << 20));  // 16 MB
  ushort_t* vT  = (ushort_t*)(ws + (size_t)(72) * (1 << 20));  // 16 MB [BH][HD][S]
  ushort_t* ao  = (ushort_t*)(ws + (size_t)(88) * (1 << 20));  // 16 MB [B,S,H,HD]
  ushort_t* x2b = (ushort_t*)(ws + (size_t)(104)* (1 << 20));  // 16 MB [M][D] bf16 residual
  ushort_t* hb  = (ushort_t*)(ws + (size_t)(136)* (1 << 20));  // 64 MB [M][DF]

  dim3 blk(256), blk5(512);
  TP4 tp;
  tp.src[0] = Wq; tp.src[1] = Wk; tp.src[2] = Wv; tp.src[3] = Wo;
  tp.dst[0] = WqT; tp.dst[1] = WkT; tp.dst[2] = WvT; tp.dst[3] = WoT;
  transpose_cvt4<<<dim3(D_/32, D_/32, 4), blk, 0, stream>>>(tp);
  transpose_cvt<<<dim3(DF_/32, D_/32),  blk, 0, stream>>>(W1, W1T, D_, DF_);
  transpose_cvt<<<dim3(D_/32,  DF_/32), blk, 0, stream>>>(W2, W2T, DF_, D_);

  // LN1 (fp32 in)
  ln_kernel<0><<<M_, blk, 0, stream>>>(x, ln1g, ln1b, xn);
  // fused QKV projection (Q pre-scaled by FA_SCALE in epilogue): 12x32 = 384 blocks
  gemm256<5><<<dim3(3072/256, M_/256), blk5, 0, stream>>>(
      xn, WqT, bq, bk, bv, nullptr, nullptr, nullptr, qT, kT, vT, M_, 3072, D_);
  // attention
  flash_attn<<<dim3(B_*H_, S_/128), blk, 0, stream>>>(qT, kT, vT, ao);
  // output projection + residual -> bf16 x2: 4x32 = 128 blocks
  gemm256<2><<<dim3(D_/256, M_/256), blk5, 0, stream>>>(
      ao, WoT, bo, nullptr, nullptr, x, nullptr, nullptr, x2b, nullptr, nullptr, M_, D_, D_);
  // LN2 (bf16 in)
  ln_kernel<1><<<M_, blk, 0, stream>>>(x2b, ln2g, ln2b, xn);
  // FFN1: 16x32 = 512 blocks
  gemm256<3><<<dim3(DF_/256, M_/256), blk5, 0, stream>>>(
      xn, W1T, b1, nullptr, nullptr, nullptr, nullptr, nullptr, hb, nullptr, nullptr, M_, DF_, D_);
  // FFN2: 4x32 = 128 blocks, K=4096
  gemm256<4><<<dim3(D_/256, M_/256), blk5, 0, stream>>>(
      hb, W2T, b2, nullptr, nullptr, nullptr, x2b, out, nullptr, nullptr, nullptr, M_, D_, DF_);
}

// Round 2
// 499.380 us; speedup vs baseline: 1.1456x; 1.0974x over previous
//
#include <hip/hip_runtime.h>
#include <math.h>

#define B_  4
#define S_  2048
#define D_  1024
#define H_  16
#define HD_ 64
#define DF_ 4096
#define M_  (B_*S_)   // 8192 rows

typedef unsigned short ushort_t;
typedef __bf16 bf16x8 __attribute__((ext_vector_type(8)));
typedef float  f32x4  __attribute__((ext_vector_type(4)));
typedef unsigned u32x4 __attribute__((ext_vector_type(4)));

#define FA_SCALE 0.18033688011112042f  // (1/8) * log2(e)

__device__ __forceinline__ ushort_t f2bf(float f) {
  union { float f; unsigned u; } v; v.f = f;
  unsigned r = v.u + 0x7FFFu + ((v.u >> 16) & 1u);
  return (ushort_t)(r >> 16);
}

__device__ __forceinline__ float bf2f(ushort_t u) {
  union { unsigned u; float f; } v; v.u = ((unsigned)u) << 16; return v.f;
}

// round-half-up bf16 pack of two floats -> u32 (lo = a, hi = b), 3 VALU ops
__device__ __forceinline__ unsigned pack_bf2(float a, float b) {
  union { float f; unsigned u; } ua, ub; ua.f = a; ub.f = b;
  return __builtin_amdgcn_perm(ub.u + 0x8000u, ua.u + 0x8000u, 0x07060302u);
}

__device__ __forceinline__ float fexp2(float x) {
#if __has_builtin(__builtin_amdgcn_exp2f)
  return __builtin_amdgcn_exp2f(x);
#else
  return __expf(x * 0.6931471805599453f);
#endif
}

// tanh-form GELU via exp2+rcp: ~5 VALU ops
__device__ __forceinline__ float fgelu(float x) {
  float e = fexp2(x * fmaf(x * x, -0.10295358f, -2.30221510f));
  return x * __builtin_amdgcn_rcpf(1.0f + e);
}

__device__ __forceinline__ void gload16(const void* g, void* l) {
  __builtin_amdgcn_global_load_lds(
      (const __attribute__((address_space(1))) void*)g,
      (__attribute__((address_space(3))) void*)l, 16, 0, 0);
}

#define PBAR() do { asm volatile("" ::: "memory"); \
                    __builtin_amdgcn_s_barrier();  \
                    asm volatile("" ::: "memory"); } while (0)

// ---------------- fp32 [R][C] -> bf16 [C][R] transpose+convert ----------------
__global__ __launch_bounds__(256) void transpose_cvt(
    const float* __restrict__ in, ushort_t* __restrict__ out, int R, int C) {
  __shared__ float tile[32][33];
  int tx = threadIdx.x & 31, ty = threadIdx.x >> 5;
  int r0 = blockIdx.y * 32, c0 = blockIdx.x * 32;
  #pragma unroll
  for (int i = 0; i < 32; i += 8)
    tile[ty + i][tx] = in[(size_t)(r0 + ty + i) * C + c0 + tx];
  __syncthreads();
  #pragma unroll
  for (int i = 0; i < 32; i += 8)
    out[(size_t)(c0 + ty + i) * R + r0 + tx] = f2bf(tile[tx][ty + i]);
}

struct TP4 { const float* src[4]; ushort_t* dst[4]; };
__global__ __launch_bounds__(256) void transpose_cvt4(TP4 p) {
  __shared__ float tile[32][33];
  const float* in = p.src[blockIdx.z];
  ushort_t* out = p.dst[blockIdx.z];
  int tx = threadIdx.x & 31, ty = threadIdx.x >> 5;
  int r0 = blockIdx.y * 32, c0 = blockIdx.x * 32;
  #pragma unroll
  for (int i = 0; i < 32; i += 8)
    tile[ty + i][tx] = in[(size_t)(r0 + ty + i) * D_ + c0 + tx];
  __syncthreads();
  #pragma unroll
  for (int i = 0; i < 32; i += 8)
    out[(size_t)(c0 + ty + i) * D_ + r0 + tx] = f2bf(tile[tx][ty + i]);
}

// ---------------- layernorm row(1024) -> bf16 (fp32 or bf16 input) ----------------
template <int BF_IN>
__global__ __launch_bounds__(256) void ln_kernel(
    const void* __restrict__ xv, const float* __restrict__ g,
    const float* __restrict__ b, ushort_t* __restrict__ out) {
  int row = blockIdx.x;
  int t = threadIdx.x;
  float4 v;
  if constexpr (BF_IN) {
    ushort4 raw = ((const ushort4*)((const ushort_t*)xv + (size_t)row * D_))[t];
    v.x = bf2f(raw.x); v.y = bf2f(raw.y); v.z = bf2f(raw.z); v.w = bf2f(raw.w);
  } else {
    v = ((const float4*)((const float*)xv + (size_t)row * D_))[t];
  }
  float s  = v.x + v.y + v.z + v.w;
  float ss = v.x*v.x + v.y*v.y + v.z*v.z + v.w*v.w;
  #pragma unroll
  for (int off = 32; off > 0; off >>= 1) {
    s  += __shfl_down(s, off);
    ss += __shfl_down(ss, off);
  }
  __shared__ float sh[8];
  int w = t >> 6, lane = t & 63;
  if (lane == 0) { sh[w] = s; sh[4 + w] = ss; }
  __syncthreads();
  if (t == 0) {
    float a  = sh[0] + sh[1] + sh[2] + sh[3];
    float a2 = sh[4] + sh[5] + sh[6] + sh[7];
    float mean = a * (1.0f / D_);
    float var  = a2 * (1.0f / D_) - mean * mean;
    sh[0] = mean; sh[1] = rsqrtf(var + 1e-5f);
  }
  __syncthreads();
  float mean = sh[0], rstd = sh[1];
  float4 gv = ((const float4*)g)[t];
  float4 bv = ((const float4*)b)[t];
  ushort4 o;
  o.x = f2bf((v.x - mean) * rstd * gv.x + bv.x);
  o.y = f2bf((v.y - mean) * rstd * gv.y + bv.y);
  o.z = f2bf((v.z - mean) * rstd * gv.z + bv.z);
  o.w = f2bf((v.w - mean) * rstd * gv.w + bv.w);
  ((ushort4*)(out + (size_t)row * D_))[t] = o;
}

// ---------------- GEMM 256x256, BK=64, 8 waves, phase-pipelined ----------------
// (used for FFN1 only: grid 512 = 2 exact block-waves over 256 CUs)
template <int MODE>
__global__ __launch_bounds__(512, 2) void gemm256(
    const ushort_t* __restrict__ A, const ushort_t* __restrict__ BT,
    const float* __restrict__ b0, const float* __restrict__ b1,
    const float* __restrict__ b2, const float* __restrict__ resF,
    const ushort_t* __restrict__ resB,
    float* __restrict__ outF, ushort_t* __restrict__ o0,
    ushort_t* __restrict__ o1, ushort_t* __restrict__ o2,
    int M, int N, int K) {
  __shared__ __align__(16) ushort_t lds[2][2][256 * 64];  // [buf][A/B][row*64+chunk*8]
  const int t = threadIdx.x;
  const int lane = t & 63, w = t >> 6;
  const int wy = w >> 2, wx = w & 3;
  const int q8 = lane >> 4, l16 = lane & 15;
  const int c7 = l16 & 7;

  const int nX = gridDim.x;
  const int lin = blockIdx.y * nX + blockIdx.x;
  const int cpx = (nX * gridDim.y) >> 3;   // nwg % 8 == 0 for all call sites
  const int L = (lin & 7) * cpx + (lin >> 3);
  const int n0 = (L % nX) * 256;
  const int m0 = (L / nX) * 256;

  const int srow = lane >> 3;
  const int schk = (lane & 7) ^ srow;
  const ushort_t* Ab = A  + (size_t)(m0 + w * 8 + srow) * K + schk * 8;
  const ushort_t* Bb = BT + (size_t)(n0 + w * 8 + srow) * K + schk * 8;

  auto stageA = [&](int k0, int buf, int half) {
    #pragma unroll
    for (int i = half * 2; i < half * 2 + 2; ++i)
      gload16(Ab + (size_t)(i * 64) * K + k0, &lds[buf][0][(i * 64 + w * 8) * 64]);
  };
  auto stageB = [&](int k0, int buf, int half) {
    #pragma unroll
    for (int i = half * 2; i < half * 2 + 2; ++i)
      gload16(Bb + (size_t)(i * 64) * K + k0, &lds[buf][1][(i * 64 + w * 8) * 64]);
  };

  auto ldA = [&](int buf, int mh, bf16x8 (&A4)[4][2]) {
    #pragma unroll
    for (int mi = 0; mi < 4; ++mi) {
      const ushort_t* p = &lds[buf][0][(wy * 128 + mh * 64 + mi * 16 + l16) * 64];
      A4[mi][0] = *(const bf16x8*)(p + ((q8 ^ c7) << 3));
      A4[mi][1] = *(const bf16x8*)(p + (((4 + q8) ^ c7) << 3));
    }
  };
  auto ldB = [&](int buf, int nh, bf16x8 (&B2)[2][2]) {
    #pragma unroll
    for (int ni = 0; ni < 2; ++ni) {
      const ushort_t* p = &lds[buf][1][(wx * 64 + nh * 32 + ni * 16 + l16) * 64];
      B2[ni][0] = *(const bf16x8*)(p + ((q8 ^ c7) << 3));
      B2[ni][1] = *(const bf16x8*)(p + (((4 + q8) ^ c7) << 3));
    }
  };

  f32x4 acc[8][4] = {};
  auto mfmaQ = [&](int mh, int nh, bf16x8 (&A4)[4][2], bf16x8 (&B2)[2][2]) {
    #pragma unroll
    for (int mi = 0; mi < 4; ++mi)
      #pragma unroll
      for (int ni = 0; ni < 2; ++ni) {
        f32x4 c = acc[mh * 4 + mi][nh * 2 + ni];
        c = __builtin_amdgcn_mfma_f32_16x16x32_bf16(B2[ni][0], A4[mi][0], c, 0, 0, 0);
        c = __builtin_amdgcn_mfma_f32_16x16x32_bf16(B2[ni][1], A4[mi][1], c, 0, 0, 0);
        acc[mh * 4 + mi][nh * 2 + ni] = c;
      }
  };

  const int nT = K >> 6;
  stageA(0, 0, 0); stageA(0, 0, 1);
  stageB(0, 0, 0); stageB(0, 0, 1);
  if (nT > 1) { stageB(64, 1, 0); stageB(64, 1, 1); }

  bf16x8 bA[4][2];
  bf16x8 bB[2][2][2];  // [nh][ni][kk]

  for (int U = 0; U < nT; ++U) {
    const int buf = U & 1;
    if (U == nT - 1) asm volatile("s_waitcnt vmcnt(0)" ::: "memory");
    else             asm volatile("s_waitcnt vmcnt(4)" ::: "memory");
    __builtin_amdgcn_s_barrier();
    asm volatile("" ::: "memory");
    // ---- P1: Q(0,0)
    ldB(buf, 0, bB[0]);
    ldA(buf, 0, bA);
    if (U + 1 < nT) stageA((U + 1) << 6, buf ^ 1, 0);
    __builtin_amdgcn_s_setprio(1);
    mfmaQ(0, 0, bA, bB[0]);
    __builtin_amdgcn_s_setprio(0);
    PBAR();
    // ---- P2: Q(0,1)
    ldB(buf, 1, bB[1]);
    if (U + 1 < nT) stageA((U + 1) << 6, buf ^ 1, 1);
    __builtin_amdgcn_s_setprio(1);
    mfmaQ(0, 1, bA, bB[1]);
    __builtin_amdgcn_s_setprio(0);
    PBAR();
    // ---- P3: Q(1,1)
    ldA(buf, 1, bA);
    if (U + 2 < nT) stageB((U + 2) << 6, buf, 0);
    __builtin_amdgcn_s_setprio(1);
    mfmaQ(1, 1, bA, bB[1]);
    __builtin_amdgcn_s_setprio(0);
    PBAR();
    // ---- P4: Q(1,0)
    if (U + 2 < nT) stageB((U + 2) << 6, buf, 1);
    __builtin_amdgcn_s_setprio(1);
    mfmaQ(1, 0, bA, bB[0]);
    __builtin_amdgcn_s_setprio(0);
  }

  // epilogue (acc: reg r -> n, l16 -> m); only MODE 3 instantiated here
  {
    #pragma unroll
    for (int ni = 0; ni < 4; ++ni) {
      int n = n0 + wx * 64 + ni * 16 + q8 * 4;
      float4 bb = *(const float4*)(b0 + n);
      #pragma unroll
      for (int mi = 0; mi < 8; ++mi) {
        int m = m0 + wy * 128 + mi * 16 + l16;
        size_t idx = (size_t)m * N + n;
        f32x4 a = acc[mi][ni];
        if constexpr (MODE == 2) {
          float4 r4 = *(const float4*)(resF + idx);
          uint2 pk;
          pk.x = pack_bf2(r4.x + a[0] + bb.x, r4.y + a[1] + bb.y);
          pk.y = pack_bf2(r4.z + a[2] + bb.z, r4.w + a[3] + bb.w);
          *(uint2*)(o0 + idx) = pk;
        } else if constexpr (MODE == 4) {
          ushort4 r4 = *(const ushort4*)(resB + idx);
          float4 o4;
          o4.x = bf2f(r4.x) + a[0] + bb.x;
          o4.y = bf2f(r4.y) + a[1] + bb.y;
          o4.z = bf2f(r4.z) + a[2] + bb.z;
          o4.w = bf2f(r4.w) + a[3] + bb.w;
          *(float4*)(outF + idx) = o4;
        } else {  // MODE 3
          uint2 pk;
          pk.x = pack_bf2(fgelu(a[0] + bb.x), fgelu(a[1] + bb.y));
          pk.y = pack_bf2(fgelu(a[2] + bb.z), fgelu(a[3] + bb.w));
          *(uint2*)(o0 + idx) = pk;
        }
      }
    }
  }
}

// ---------------- GEMM 128x256, BK=64, 8 waves, 2-phase pipelined ----------------
// For narrow-N GEMMs where 256x256 leaves CUs idle. Per-wave tile 64x64
// (wy in 0..1 -> 64 rows, wx in 0..3 -> 64 cols), acc[4][4].
// A double-buffered (16 KiB x2), B TRIPLE-buffered (32 KiB x3) = 128 KiB LDS.
// Per K-tile U (2 phases, 16 MFMA each):
//   P1: ldA(all) + ldB(nh0) | stage A(U+1)->A^1, B(U+2,h0)->B(U+2)%3 | MFMA ni{0,1}
//   P2: ldB(nh1)            | stage B(U+2,h1)                        | MFMA ni{2,3}
// WAR: A[bufA^1] free after tile U-1's P1; B[(U+2)%3] holds B(U-1), free at tile U.
// RAW boundary: A(U) issued tile U-1 P1, B(U) issued tile U-2; outstanding
// beyond = B(U+1)'s 4 loads -> vmcnt(4) steady, vmcnt(0) at last tile.
template <int MODE>
__global__ __launch_bounds__(512, 2) void gemm128(
    const ushort_t* __restrict__ A, const ushort_t* __restrict__ BT,
    const float* __restrict__ b0, const float* __restrict__ b1,
    const float* __restrict__ b2, const float* __restrict__ resF,
    const ushort_t* __restrict__ resB,
    float* __restrict__ outF, ushort_t* __restrict__ o0,
    ushort_t* __restrict__ o1, ushort_t* __restrict__ o2,
    int M, int N, int K) {
  __shared__ __align__(16) ushort_t lsA[2][128 * 64];
  __shared__ __align__(16) ushort_t lsB[3][256 * 64];
  const int t = threadIdx.x;
  const int lane = t & 63, w = t >> 6;
  const int wy = w >> 2, wx = w & 3;
  const int q8 = lane >> 4, l16 = lane & 15;
  const int c7 = l16 & 7;

  const int nX = gridDim.x;
  const int lin = blockIdx.y * nX + blockIdx.x;
  const int cpx = (nX * gridDim.y) >> 3;   // nwg % 8 == 0 at all call sites
  const int L = (lin & 7) * cpx + (lin >> 3);
  const int n0 = (L % nX) * 256;
  const int m0 = (L / nX) * 128;

  const int srow = lane >> 3;
  const int schk = (lane & 7) ^ srow;
  const ushort_t* Ab = A  + (size_t)(m0 + w * 8 + srow) * K + schk * 8;
  const ushort_t* Bb = BT + (size_t)(n0 + w * 8 + srow) * K + schk * 8;

  auto stageA = [&](int k0, int buf) {
    #pragma unroll
    for (int i = 0; i < 2; ++i)
      gload16(Ab + (size_t)(i * 64) * K + k0, &lsA[buf][(i * 64 + w * 8) * 64]);
  };
  auto stageB = [&](int k0, int buf, int half) {
    #pragma unroll
    for (int i = half * 2; i < half * 2 + 2; ++i)
      gload16(Bb + (size_t)(i * 64) * K + k0, &lsB[buf][(i * 64 + w * 8) * 64]);
  };

  auto ldA = [&](int buf, bf16x8 (&A4)[4][2]) {
    #pragma unroll
    for (int mi = 0; mi < 4; ++mi) {
      const ushort_t* p = &lsA[buf][(wy * 64 + mi * 16 + l16) * 64];
      A4[mi][0] = *(const bf16x8*)(p + ((q8 ^ c7) << 3));
      A4[mi][1] = *(const bf16x8*)(p + (((4 + q8) ^ c7) << 3));
    }
  };
  auto ldB = [&](int buf, int nh, bf16x8 (&B2)[2][2]) {
    #pragma unroll
    for (int ni = 0; ni < 2; ++ni) {
      const ushort_t* p = &lsB[buf][(wx * 64 + nh * 32 + ni * 16 + l16) * 64];
      B2[ni][0] = *(const bf16x8*)(p + ((q8 ^ c7) << 3));
      B2[ni][1] = *(const bf16x8*)(p + (((4 + q8) ^ c7) << 3));
    }
  };

  f32x4 acc[4][4] = {};
  auto mfmaH = [&](int nh, bf16x8 (&A4)[4][2], bf16x8 (&B2)[2][2]) {
    #pragma unroll
    for (int mi = 0; mi < 4; ++mi)
      #pragma unroll
      for (int ni = 0; ni < 2; ++ni) {
        f32x4 c = acc[mi][nh * 2 + ni];
        c = __builtin_amdgcn_mfma_f32_16x16x32_bf16(B2[ni][0], A4[mi][0], c, 0, 0, 0);
        c = __builtin_amdgcn_mfma_f32_16x16x32_bf16(B2[ni][1], A4[mi][1], c, 0, 0, 0);
        acc[mi][nh * 2 + ni] = c;
      }
  };

  const int nT = K >> 6;
  // prologue: A(0)->A0, B(0)->B0, B(1)->B1. Steady-state: everything for tile
  // U+1 except B(U+1) is older than the newest 4 loads.
  stageA(0, 0);
  stageB(0, 0, 0); stageB(0, 0, 1);
  stageB(64, 1, 0); stageB(64, 1, 1);

  bf16x8 bA[4][2];
  bf16x8 bB0[2][2], bB1[2][2];

  int bufB = 0;
  for (int U = 0; U < nT; ++U) {
    const int bufA = U & 1;
    if (U == nT - 1) asm volatile("s_waitcnt vmcnt(0)" ::: "memory");
    else             asm volatile("s_waitcnt vmcnt(4)" ::: "memory");
    __builtin_amdgcn_s_barrier();
    asm volatile("" ::: "memory");
    int bufB2 = bufB + 2; if (bufB2 >= 3) bufB2 -= 3;   // (U+2)%3
    // ---- P1: ni {0,1}
    ldA(bufA, bA);
    ldB(bufB, 0, bB0);
    if (U + 1 < nT) stageA((U + 1) << 6, bufA ^ 1);
    if (U + 2 < nT) stageB((U + 2) << 6, bufB2, 0);
    __builtin_amdgcn_s_setprio(1);
    mfmaH(0, bA, bB0);
    __builtin_amdgcn_s_setprio(0);
    PBAR();
    // ---- P2: ni {2,3}
    ldB(bufB, 1, bB1);
    if (U + 2 < nT) stageB((U + 2) << 6, bufB2, 1);
    __builtin_amdgcn_s_setprio(1);
    mfmaH(1, bA, bB1);
    __builtin_amdgcn_s_setprio(0);
    bufB = (bufB == 2) ? 0 : bufB + 1;
  }

  // ---------------- epilogues (acc layout: reg r -> n, l16 -> m) ----------------
  if constexpr (MODE == 5) {
    const int kind = n0 >> 10;                       // block-uniform (BN=256 aligned)
    const float* bp = (kind == 0) ? b0 : (kind == 1) ? b1 : b2;
    ushort_t* dst = (kind == 0) ? o0 : (kind == 1) ? o1 : o2;
    #pragma unroll
    for (int ni = 0; ni < 4; ++ni) {
      int nn = (n0 & 1023) + wx * 64 + ni * 16 + q8 * 4;
      int h = nn >> 6, hd = nn & 63;
      float4 bb = *(const float4*)(bp + nn);
      #pragma unroll
      for (int mi = 0; mi < 4; ++mi) {
        int m = m0 + wy * 64 + mi * 16 + l16;
        int b = m >> 11, s = m & (S_ - 1);
        f32x4 a = acc[mi][ni];
        float v0 = a[0] + bb.x, v1 = a[1] + bb.y, v2 = a[2] + bb.z, v3 = a[3] + bb.w;
        if (kind == 0) { v0 *= FA_SCALE; v1 *= FA_SCALE; v2 *= FA_SCALE; v3 *= FA_SCALE; }
        if (kind == 2) {
          size_t base = ((size_t)(b * H_ + h) * HD_ + hd) * S_ + s;
          dst[base]          = f2bf(v0);
          dst[base + S_]     = f2bf(v1);
          dst[base + 2 * S_] = f2bf(v2);
          dst[base + 3 * S_] = f2bf(v3);
        } else {
          uint2 pk;
          pk.x = pack_bf2(v0, v1);
          pk.y = pack_bf2(v2, v3);
          *(uint2*)(dst + ((size_t)(b * H_ + h) * S_ + s) * HD_ + hd) = pk;
        }
      }
    }
  } else {
    #pragma unroll
    for (int ni = 0; ni < 4; ++ni) {
      int n = n0 + wx * 64 + ni * 16 + q8 * 4;
      float4 bb = *(const float4*)(b0 + n);
      #pragma unroll
      for (int mi = 0; mi < 4; ++mi) {
        int m = m0 + wy * 64 + mi * 16 + l16;
        size_t idx = (size_t)m * N + n;
        f32x4 a = acc[mi][ni];
        if constexpr (MODE == 2) {
          float4 r4 = *(const float4*)(resF + idx);
          uint2 pk;
          pk.x = pack_bf2(r4.x + a[0] + bb.x, r4.y + a[1] + bb.y);
          pk.y = pack_bf2(r4.z + a[2] + bb.z, r4.w + a[3] + bb.w);
          *(uint2*)(o0 + idx) = pk;
        } else if constexpr (MODE == 4) {
          ushort4 r4 = *(const ushort4*)(resB + idx);
          float4 o4;
          o4.x = bf2f(r4.x) + a[0] + bb.x;
          o4.y = bf2f(r4.y) + a[1] + bb.y;
          o4.z = bf2f(r4.z) + a[2] + bb.z;
          o4.w = bf2f(r4.w) + a[3] + bb.w;
          *(float4*)(outF + idx) = o4;
        } else {  // MODE 3
          uint2 pk;
          pk.x = pack_bf2(fgelu(a[0] + bb.x), fgelu(a[1] + bb.y));
          pk.y = pack_bf2(fgelu(a[2] + bb.z), fgelu(a[3] + bb.w));
          *(uint2*)(o0 + idx) = pk;
        }
      }
    }
  }
}

// ---------------- flash attention v4 (register-resident P, 32 KB LDS) ----------------
__global__ __launch_bounds__(256) void flash_attn(
    const ushort_t* __restrict__ Qt, const ushort_t* __restrict__ Kt,
    const ushort_t* __restrict__ Vt, ushort_t* __restrict__ Ao) {
  __shared__ __align__(16) ushort_t ks[2][64 * 64];
  __shared__ __align__(16) ushort_t vs[2][64 * 64];
  const int t = threadIdx.x;
  const int lane = t & 63, w = t >> 6;
  const int q8 = lane >> 4, l16 = lane & 15;
  const int bh = blockIdx.x, q0 = blockIdx.y * 128;
  const int c7 = l16 & 7;
  const int koff0 = ((q8)     ^ c7) * 8;
  const int koff1 = ((4 + q8) ^ c7) * 8;
  const int half4 = (q8 & 1) * 4;
  const int voff00 = (((q8 >> 1)    ) ^ c7) * 8 + half4;
  const int voff01 = (((q8 >> 1) + 2) ^ c7) * 8 + half4;
  const int voff10 = (((q8 >> 1) + 4) ^ c7) * 8 + half4;
  const int voff11 = (((q8 >> 1) + 6) ^ c7) * 8 + half4;

  bf16x8 bq[2][2];
  #pragma unroll
  for (int u = 0; u < 2; ++u)
    #pragma unroll
    for (int kc = 0; kc < 2; ++kc) {
      int row = q0 + w * 32 + u * 16 + l16;
      bq[u][kc] = *(const bf16x8*)(Qt + ((size_t)bh * S_ + row) * HD_ + kc * 32 + q8 * 8);
    }

  const ushort_t* Kg = Kt + (size_t)bh * S_ * HD_;
  const ushort_t* Vg = Vt + (size_t)bh * HD_ * S_;

  #pragma unroll
  for (int i = 0; i < 2; ++i) {
    int slot = i * 256 + t;
    int row = slot >> 3, gch = (slot & 7) ^ (row & 7);
    gload16(Kg + row * HD_ + gch * 8,        ks[0] + (i * 256 + w * 64) * 8);
    gload16(Vg + (size_t)row * S_ + gch * 8, vs[0] + (i * 256 + w * 64) * 8);
  }

  bf16x8 kone;
  #pragma unroll
  for (int i = 0; i < 8; ++i) kone[i] = (__bf16)1.0f;

  f32x4 accO[2][4] = {};
  f32x4 accL[2] = {};

  for (int it = 0; it < S_ / 64; ++it) {
    __syncthreads();
    const int cur = it & 1;
    if (it + 1 < S_ / 64) {
      const ushort_t* Kn = Kg + (size_t)(it + 1) * 64 * HD_;
      const ushort_t* Vn = Vg + (it + 1) * 64;
      #pragma unroll
      for (int i = 0; i < 2; ++i) {
        int slot = i * 256 + t;
        int row = slot >> 3, gch = (slot & 7) ^ (row & 7);
        gload16(Kn + row * HD_ + gch * 8,        ks[cur ^ 1] + (i * 256 + w * 64) * 8);
        gload16(Vn + (size_t)row * S_ + gch * 8, vs[cur ^ 1] + (i * 256 + w * 64) * 8);
      }
    }
    const ushort_t* kbuf = ks[cur];
    const ushort_t* vbuf = vs[cur];

    f32x4 st[2][4];
    #pragma unroll
    for (int ni = 0; ni < 4; ++ni) {
      const ushort_t* kr = kbuf + (ni * 16 + l16) * 64;
      bf16x8 ak0 = *(const bf16x8*)(kr + koff0);
      bf16x8 ak1 = *(const bf16x8*)(kr + koff1);
      #pragma unroll
      for (int u = 0; u < 2; ++u) {
        f32x4 z = {0.f, 0.f, 0.f, 0.f};
        z = __builtin_amdgcn_mfma_f32_16x16x32_bf16(ak0, bq[u][0], z, 0, 0, 0);
        z = __builtin_amdgcn_mfma_f32_16x16x32_bf16(ak1, bq[u][1], z, 0, 0, 0);
        st[u][ni] = z;
      }
    }
    bf16x8 bp[2][2];
    #pragma unroll
    for (int u = 0; u < 2; ++u) {
      uint2 pk[4];
      #pragma unroll
      for (int ni = 0; ni < 4; ++ni) {
        pk[ni].x = pack_bf2(fexp2(st[u][ni][0]), fexp2(st[u][ni][1]));
        pk[ni].y = pack_bf2(fexp2(st[u][ni][2]), fexp2(st[u][ni][3]));
      }
      u32x4 d0 = {pk[0].x, pk[0].y, pk[1].x, pk[1].y};
      u32x4 d1 = {pk[2].x, pk[2].y, pk[3].x, pk[3].y};
      bp[u][0] = __builtin_bit_cast(bf16x8, d0);
      bp[u][1] = __builtin_bit_cast(bf16x8, d1);
    }
    #pragma unroll
    for (int u = 0; u < 2; ++u) {
      accL[u] = __builtin_amdgcn_mfma_f32_16x16x32_bf16(kone, bp[u][0], accL[u], 0, 0, 0);
      accL[u] = __builtin_amdgcn_mfma_f32_16x16x32_bf16(kone, bp[u][1], accL[u], 0, 0, 0);
    }
    #pragma unroll
    for (int ni = 0; ni < 4; ++ni) {
      const ushort_t* vr = vbuf + (ni * 16 + l16) * 64;
      uint2 lo0 = *(const uint2*)(vr + voff00);
      uint2 hi0 = *(const uint2*)(vr + voff01);
      uint2 lo1 = *(const uint2*)(vr + voff10);
      uint2 hi1 = *(const uint2*)(vr + voff11);
      u32x4 a0 = {lo0.x, lo0.y, hi0.x, hi0.y};
      u32x4 a1 = {lo1.x, lo1.y, hi1.x, hi1.y};
      bf16x8 av0 = __builtin_bit_cast(bf16x8, a0);
      bf16x8 av1 = __builtin_bit_cast(bf16x8, a1);
      #pragma unroll
      for (int u = 0; u < 2; ++u) {
        accO[u][ni] = __builtin_amdgcn_mfma_f32_16x16x32_bf16(av0, bp[u][0], accO[u][ni], 0, 0, 0);
        accO[u][ni] = __builtin_amdgcn_mfma_f32_16x16x32_bf16(av1, bp[u][1], accO[u][ni], 0, 0, 0);
      }
    }
  }

  const int b = bh >> 4, h = bh & 15;
  #pragma unroll
  for (int u = 0; u < 2; ++u) {
    float inv = 1.0f / accL[u][0];
    int q = q0 + w * 32 + u * 16 + l16;
    #pragma unroll
    for (int ni = 0; ni < 4; ++ni) {
      uint2 pk;
      pk.x = pack_bf2(accO[u][ni][0] * inv, accO[u][ni][1] * inv);
      pk.y = pack_bf2(accO[u][ni][2] * inv, accO[u][ni][3] * inv);
      *(uint2*)(Ao + (((size_t)b * S_ + q) * H_ + h) * HD_ + ni * 16 + q8 * 4) = pk;
    }
  }
}

extern "C" void kernel_launch(void* const* d_in, const int* in_sizes, int n_in,
                              void* d_out, int out_size, void* d_ws, size_t ws_size,
                              hipStream_t stream) {
  const float* x    = (const float*)d_in[0];
  const float* Wq   = (const float*)d_in[1];
  const float* bq   = (const float*)d_in[2];
  const float* Wk   = (const float*)d_in[3];
  const float* bk   = (const float*)d_in[4];
  const float* Wv   = (const float*)d_in[5];
  const float* bv   = (const float*)d_in[6];
  const float* Wo   = (const float*)d_in[7];
  const float* bo   = (const float*)d_in[8];
  const float* ln1g = (const float*)d_in[9];
  const float* ln1b = (const float*)d_in[10];
  const float* ln2g = (const float*)d_in[11];
  const float* ln2b = (const float*)d_in[12];
  const float* W1   = (const float*)d_in[13];
  const float* b1   = (const float*)d_in[14];
  const float* W2   = (const float*)d_in[15];
  const float* b2   = (const float*)d_in[16];
  float* out = (float*)d_out;

  char* ws = (char*)d_ws;
  ushort_t* WqT = (ushort_t*)(ws + (size_t)(0)  * (1 << 20));  // 2 MB  } contiguous
  ushort_t* WkT = (ushort_t*)(ws + (size_t)(2)  * (1 << 20));  // 2 MB  } [3072][1024]
  ushort_t* WvT = (ushort_t*)(ws + (size_t)(4)  * (1 << 20));  // 2 MB  } fused QKV
  ushort_t* WoT = (ushort_t*)(ws + (size_t)(6)  * (1 << 20));  // 2 MB
  ushort_t* W1T = (ushort_t*)(ws + (size_t)(8)  * (1 << 20));  // 8 MB  [DF][D]
  ushort_t* W2T = (ushort_t*)(ws + (size_t)(16) * (1 << 20));  // 8 MB  [D][DF]
  ushort_t* xn  = (ushort_t*)(ws + (size_t)(24) * (1 << 20));  // 16 MB [M][D]
  ushort_t* qT  = (ushort_t*)(ws + (size_t)(40) * (1 << 20));  // 16 MB [BH][S][HD]
  ushort_t* kT  = (ushort_t*)(ws + (size_t)(56) * (1 << 20));  // 16 MB
  ushort_t* vT  = (ushort_t*)(ws + (size_t)(72) * (1 << 20));  // 16 MB [BH][HD][S]
  ushort_t* ao  = (ushort_t*)(ws + (size_t)(88) * (1 << 20));  // 16 MB [B,S,H,HD]
  ushort_t* x2b = (ushort_t*)(ws + (size_t)(104)* (1 << 20));  // 16 MB [M][D] bf16 residual
  ushort_t* hb  = (ushort_t*)(ws + (size_t)(136)* (1 << 20));  // 64 MB [M][DF]

  dim3 blk(256), blk5(512);
  TP4 tp;
  tp.src[0] = Wq; tp.src[1] = Wk; tp.src[2] = Wv; tp.src[3] = Wo;
  tp.dst[0] = WqT; tp.dst[1] = WkT; tp.dst[2] = WvT; tp.dst[3] = WoT;
  transpose_cvt4<<<dim3(D_/32, D_/32, 4), blk, 0, stream>>>(tp);
  transpose_cvt<<<dim3(DF_/32, D_/32),  blk, 0, stream>>>(W1, W1T, D_, DF_);
  transpose_cvt<<<dim3(D_/32,  DF_/32), blk, 0, stream>>>(W2, W2T, DF_, D_);

  // LN1 (fp32 in)
  ln_kernel<0><<<M_, blk, 0, stream>>>(x, ln1g, ln1b, xn);
  // fused QKV projection: 12x64 = 768 blocks = 3 exact block-waves
  gemm128<5><<<dim3(3072/256, M_/128), blk5, 0, stream>>>(
      xn, WqT, bq, bk, bv, nullptr, nullptr, nullptr, qT, kT, vT, M_, 3072, D_);
  // attention
  flash_attn<<<dim3(B_*H_, S_/128), blk, 0, stream>>>(qT, kT, vT, ao);
  // output projection + residual -> bf16 x2: 4x64 = 256 blocks = 1/CU
  gemm128<2><<<dim3(D_/256, M_/128), blk5, 0, stream>>>(
      ao, WoT, bo, nullptr, nullptr, x, nullptr, nullptr, x2b, nullptr, nullptr, M_, D_, D_);
  // LN2 (bf16 in)
  ln_kernel<1><<<M_, blk, 0, stream>>>(x2b, ln2g, ln2b, xn);
  // FFN1: 16x32 = 512 blocks = 2 exact block-waves (256x256 tiles)
  gemm256<3><<<dim3(DF_/256, M_/256), blk5, 0, stream>>>(
      xn, W1T, b1, nullptr, nullptr, nullptr, nullptr, nullptr, hb, nullptr, nullptr, M_, DF_, D_);
  // FFN2: 4x64 = 256 blocks = 1/CU, K=4096
  gemm128<4><<<dim3(D_/256, M_/128), blk5, 0, stream>>>(
      hb, W2T, b2, nullptr, nullptr, nullptr, x2b, out, nullptr, nullptr, nullptr, M_, D_, DF_);
}

// Round 3
// 488.734 us; speedup vs baseline: 1.1706x; 1.0218x over previous
//
#include <hip/hip_runtime.h>
#include <math.h>

#define B_  4
#define S_  2048
#define D_  1024
#define H_  16
#define HD_ 64
#define DF_ 4096
#define M_  (B_*S_)   // 8192 rows

typedef unsigned short ushort_t;
typedef __bf16 bf16x8 __attribute__((ext_vector_type(8)));
typedef float  f32x4  __attribute__((ext_vector_type(4)));
typedef unsigned u32x4 __attribute__((ext_vector_type(4)));

#define FA_SCALE 0.18033688011112042f  // (1/8) * log2(e)

__device__ __forceinline__ ushort_t f2bf(float f) {
  union { float f; unsigned u; } v; v.f = f;
  unsigned r = v.u + 0x7FFFu + ((v.u >> 16) & 1u);
  return (ushort_t)(r >> 16);
}

__device__ __forceinline__ float bf2f(ushort_t u) {
  union { unsigned u; float f; } v; v.u = ((unsigned)u) << 16; return v.f;
}

// round-half-up bf16 pack of two floats -> u32 (lo = a, hi = b), 3 VALU ops
__device__ __forceinline__ unsigned pack_bf2(float a, float b) {
  union { float f; unsigned u; } ua, ub; ua.f = a; ub.f = b;
  return __builtin_amdgcn_perm(ub.u + 0x8000u, ua.u + 0x8000u, 0x07060302u);
}

__device__ __forceinline__ float fexp2(float x) {
#if __has_builtin(__builtin_amdgcn_exp2f)
  return __builtin_amdgcn_exp2f(x);
#else
  return __expf(x * 0.6931471805599453f);
#endif
}

// tanh-form GELU via exp2+rcp: ~5 VALU ops
__device__ __forceinline__ float fgelu(float x) {
  float e = fexp2(x * fmaf(x * x, -0.10295358f, -2.30221510f));
  return x * __builtin_amdgcn_rcpf(1.0f + e);
}

__device__ __forceinline__ void gload16(const void* g, void* l) {
  __builtin_amdgcn_global_load_lds(
      (const __attribute__((address_space(1))) void*)g,
      (__attribute__((address_space(3))) void*)l, 16, 0, 0);
}

// raw barrier with compiler memory fence (no vmcnt drain)
#define BARM() do { asm volatile("" ::: "memory"); \
                    __builtin_amdgcn_s_barrier();  \
                    asm volatile("" ::: "memory"); } while (0)
#define LGKM0() asm volatile("s_waitcnt lgkmcnt(0)" ::: "memory")

// ---------------- fp32 [R][C] -> bf16 [C][R] transpose+convert ----------------
__global__ __launch_bounds__(256) void transpose_cvt(
    const float* __restrict__ in, ushort_t* __restrict__ out, int R, int C) {
  __shared__ float tile[32][33];
  int tx = threadIdx.x & 31, ty = threadIdx.x >> 5;
  int r0 = blockIdx.y * 32, c0 = blockIdx.x * 32;
  #pragma unroll
  for (int i = 0; i < 32; i += 8)
    tile[ty + i][tx] = in[(size_t)(r0 + ty + i) * C + c0 + tx];
  __syncthreads();
  #pragma unroll
  for (int i = 0; i < 32; i += 8)
    out[(size_t)(c0 + ty + i) * R + r0 + tx] = f2bf(tile[tx][ty + i]);
}

struct TP4 { const float* src[4]; ushort_t* dst[4]; };
__global__ __launch_bounds__(256) void transpose_cvt4(TP4 p) {
  __shared__ float tile[32][33];
  const float* in = p.src[blockIdx.z];
  ushort_t* out = p.dst[blockIdx.z];
  int tx = threadIdx.x & 31, ty = threadIdx.x >> 5;
  int r0 = blockIdx.y * 32, c0 = blockIdx.x * 32;
  #pragma unroll
  for (int i = 0; i < 32; i += 8)
    tile[ty + i][tx] = in[(size_t)(r0 + ty + i) * D_ + c0 + tx];
  __syncthreads();
  #pragma unroll
  for (int i = 0; i < 32; i += 8)
    out[(size_t)(c0 + ty + i) * D_ + r0 + tx] = f2bf(tile[tx][ty + i]);
}

// ---------------- layernorm row(1024) -> bf16 (fp32 or bf16 input) ----------------
template <int BF_IN>
__global__ __launch_bounds__(256) void ln_kernel(
    const void* __restrict__ xv, const float* __restrict__ g,
    const float* __restrict__ b, ushort_t* __restrict__ out) {
  int row = blockIdx.x;
  int t = threadIdx.x;
  float4 v;
  if constexpr (BF_IN) {
    ushort4 raw = ((const ushort4*)((const ushort_t*)xv + (size_t)row * D_))[t];
    v.x = bf2f(raw.x); v.y = bf2f(raw.y); v.z = bf2f(raw.z); v.w = bf2f(raw.w);
  } else {
    v = ((const float4*)((const float*)xv + (size_t)row * D_))[t];
  }
  float s  = v.x + v.y + v.z + v.w;
  float ss = v.x*v.x + v.y*v.y + v.z*v.z + v.w*v.w;
  #pragma unroll
  for (int off = 32; off > 0; off >>= 1) {
    s  += __shfl_down(s, off);
    ss += __shfl_down(ss, off);
  }
  __shared__ float sh[8];
  int w = t >> 6, lane = t & 63;
  if (lane == 0) { sh[w] = s; sh[4 + w] = ss; }
  __syncthreads();
  if (t == 0) {
    float a  = sh[0] + sh[1] + sh[2] + sh[3];
    float a2 = sh[4] + sh[5] + sh[6] + sh[7];
    float mean = a * (1.0f / D_);
    float var  = a2 * (1.0f / D_) - mean * mean;
    sh[0] = mean; sh[1] = rsqrtf(var + 1e-5f);
  }
  __syncthreads();
  float mean = sh[0], rstd = sh[1];
  float4 gv = ((const float4*)g)[t];
  float4 bv = ((const float4*)b)[t];
  ushort4 o;
  o.x = f2bf((v.x - mean) * rstd * gv.x + bv.x);
  o.y = f2bf((v.y - mean) * rstd * gv.y + bv.y);
  o.z = f2bf((v.z - mean) * rstd * gv.z + bv.z);
  o.w = f2bf((v.w - mean) * rstd * gv.w + bv.w);
  ((ushort4*)(out + (size_t)row * D_))[t] = o;
}

// ================= GEMM 256x256, BK=64, 8 waves, m201-style 4-phase =================
// C[M,N] = A[M,K](bf16) @ BT[N,K](bf16)^T + bias. Accumulator TRANSPOSED
// (swapped MFMA operands): reg r -> n (4 consecutive), lane l16 -> m.
// Quadrant-aligned halves: A rows = mh*128 + wy*64 + mi*16 + l16 (half mh),
//                          B rows = nh*128 + wx*32 + ni*16 + l16 (half nh).
// Per K-tile U, 4 phases, each = {ds_reads | stage ONE half-tile | BAR |
// lgkmcnt(0) | setprio 16xMFMA | BAR}. Stage plan: P1: B-h1(U+1)->buf^1;
// P2: A-h0(U+2)->buf; P3: B-h0(U+2)->buf; P4: A-h1(U+2)->buf. Every staged
// region's last LDS-reader is fenced by the preceding post-MFMA barrier.
// Boundary (loop top): steady vmcnt(6) (3 half-tiles in flight), vmcnt(0)
// only at the last tile; then barrier.
template <int MODE>
__global__ __launch_bounds__(512, 2) void gemm256(
    const ushort_t* __restrict__ A, const ushort_t* __restrict__ BT,
    const float* __restrict__ b0, const float* __restrict__ b1,
    const float* __restrict__ b2, const float* __restrict__ resF,
    const ushort_t* __restrict__ resB,
    float* __restrict__ outF, ushort_t* __restrict__ o0,
    ushort_t* __restrict__ o1, ushort_t* __restrict__ o2,
    int M, int N, int K) {
  __shared__ __align__(16) ushort_t lsA[2][2][128 * 64];  // [buf][half][row*64]
  __shared__ __align__(16) ushort_t lsB[2][2][128 * 64];
  const int t = threadIdx.x;
  const int lane = t & 63, w = t >> 6;
  const int wy = w >> 2, wx = w & 3;
  const int q8 = lane >> 4, l16 = lane & 15;
  const int c7 = l16 & 7;

  const int nX = gridDim.x;
  const int lin = blockIdx.y * nX + blockIdx.x;
  const int cpx = (nX * gridDim.y) >> 3;   // nwg % 8 == 0 at all call sites
  const int L = (lin & 7) * cpx + (lin >> 3);
  const int n0 = (L % nX) * 256;
  const int m0 = (L / nX) * 256;

  const int srow = lane >> 3;
  const int schk = (lane & 7) ^ srow;
  const ushort_t* Ab = A  + (size_t)(m0 + w * 8 + srow) * K + schk * 8;
  const ushort_t* Bb = BT + (size_t)(n0 + w * 8 + srow) * K + schk * 8;

  // stage half-tile (rows half*128 .. +127), 2 gloads/wave
  auto stageA = [&](int k0, int buf, int half) {
    #pragma unroll
    for (int i = 0; i < 2; ++i)
      gload16(Ab + (size_t)((half * 2 + i) * 64) * K + k0,
              &lsA[buf][half][(i * 64 + w * 8) * 64]);
  };
  auto stageB = [&](int k0, int buf, int half) {
    #pragma unroll
    for (int i = 0; i < 2; ++i)
      gload16(Bb + (size_t)((half * 2 + i) * 64) * K + k0,
              &lsB[buf][half][(i * 64 + w * 8) * 64]);
  };

  auto ldA = [&](int buf, int mh, bf16x8 (&A4)[4][2]) {
    #pragma unroll
    for (int mi = 0; mi < 4; ++mi) {
      const ushort_t* p = &lsA[buf][mh][(wy * 64 + mi * 16 + l16) * 64];
      A4[mi][0] = *(const bf16x8*)(p + ((q8 ^ c7) << 3));
      A4[mi][1] = *(const bf16x8*)(p + (((4 + q8) ^ c7) << 3));
    }
  };
  auto ldB = [&](int buf, int nh, bf16x8 (&B2)[2][2]) {
    #pragma unroll
    for (int ni = 0; ni < 2; ++ni) {
      const ushort_t* p = &lsB[buf][nh][(wx * 32 + ni * 16 + l16) * 64];
      B2[ni][0] = *(const bf16x8*)(p + ((q8 ^ c7) << 3));
      B2[ni][1] = *(const bf16x8*)(p + (((4 + q8) ^ c7) << 3));
    }
  };

  f32x4 acc[8][4] = {};
  auto mfmaQ = [&](int mh, int nh, bf16x8 (&A4)[4][2], bf16x8 (&B2)[2][2]) {
    #pragma unroll
    for (int mi = 0; mi < 4; ++mi)
      #pragma unroll
      for (int ni = 0; ni < 2; ++ni) {
        f32x4 c = acc[mh * 4 + mi][nh * 2 + ni];
        c = __builtin_amdgcn_mfma_f32_16x16x32_bf16(B2[ni][0], A4[mi][0], c, 0, 0, 0);
        c = __builtin_amdgcn_mfma_f32_16x16x32_bf16(B2[ni][1], A4[mi][1], c, 0, 0, 0);
        acc[mh * 4 + mi][nh * 2 + ni] = c;
      }
  };

  const int nT = K >> 6;
  // prologue: tile0 {A-h0,B-h0,A-h1,B-h1}, tile1 {A-h0,B-h0,A-h1}  (nT >= 2)
  stageA(0, 0, 0); stageB(0, 0, 0); stageA(0, 0, 1); stageB(0, 0, 1);
  stageA(64, 1, 0); stageB(64, 1, 0); stageA(64, 1, 1);

  bf16x8 bA[4][2];
  bf16x8 bB[2][2][2];  // [nh][ni][kk]

  for (int U = 0; U < nT; ++U) {
    const int buf = U & 1;
    if (U == nT - 1) asm volatile("s_waitcnt vmcnt(0)" ::: "memory");
    else             asm volatile("s_waitcnt vmcnt(6)" ::: "memory");
    BARM();
    // ---- P1: Q(0,0)
    ldA(buf, 0, bA);
    ldB(buf, 0, bB[0]);
    if (U + 1 < nT) stageB((U + 1) << 6, buf ^ 1, 1);
    BARM();
    LGKM0();
    __builtin_amdgcn_s_setprio(1);
    mfmaQ(0, 0, bA, bB[0]);
    __builtin_amdgcn_s_setprio(0);
    BARM();
    // ---- P2: Q(0,1)
    ldB(buf, 1, bB[1]);
    if (U + 2 < nT) stageA((U + 2) << 6, buf, 0);
    BARM();
    LGKM0();
    __builtin_amdgcn_s_setprio(1);
    mfmaQ(0, 1, bA, bB[1]);
    __builtin_amdgcn_s_setprio(0);
    BARM();
    // ---- P3: Q(1,1)
    ldA(buf, 1, bA);
    if (U + 2 < nT) stageB((U + 2) << 6, buf, 0);
    BARM();
    LGKM0();
    __builtin_amdgcn_s_setprio(1);
    mfmaQ(1, 1, bA, bB[1]);
    __builtin_amdgcn_s_setprio(0);
    BARM();
    // ---- P4: Q(1,0)  (no ds_reads; stage only)
    if (U + 2 < nT) stageA((U + 2) << 6, buf, 1);
    BARM();
    __builtin_amdgcn_s_setprio(1);
    mfmaQ(1, 0, bA, bB[0]);
    __builtin_amdgcn_s_setprio(0);
    // boundary vmcnt + barrier at loop top
  }

  // epilogue: acc[mh*4+mi][nh*2+ni]; m = m0+mh*128+wy*64+mi*16+l16,
  //           n = n0+nh*128+wx*32+ni*16+q8*4
  {
    #pragma unroll
    for (int niG = 0; niG < 4; ++niG) {
      int n = n0 + (niG >> 1) * 128 + wx * 32 + (niG & 1) * 16 + q8 * 4;
      float4 bb = *(const float4*)(b0 + n);
      #pragma unroll
      for (int miG = 0; miG < 8; ++miG) {
        int m = m0 + (miG >> 2) * 128 + wy * 64 + (miG & 3) * 16 + l16;
        size_t idx = (size_t)m * N + n;
        f32x4 a = acc[miG][niG];
        if constexpr (MODE == 2) {
          float4 r4 = *(const float4*)(resF + idx);
          uint2 pk;
          pk.x = pack_bf2(r4.x + a[0] + bb.x, r4.y + a[1] + bb.y);
          pk.y = pack_bf2(r4.z + a[2] + bb.z, r4.w + a[3] + bb.w);
          *(uint2*)(o0 + idx) = pk;
        } else if constexpr (MODE == 4) {
          ushort4 r4 = *(const ushort4*)(resB + idx);
          float4 o4;
          o4.x = bf2f(r4.x) + a[0] + bb.x;
          o4.y = bf2f(r4.y) + a[1] + bb.y;
          o4.z = bf2f(r4.z) + a[2] + bb.z;
          o4.w = bf2f(r4.w) + a[3] + bb.w;
          *(float4*)(outF + idx) = o4;
        } else {  // MODE 3
          uint2 pk;
          pk.x = pack_bf2(fgelu(a[0] + bb.x), fgelu(a[1] + bb.y));
          pk.y = pack_bf2(fgelu(a[2] + bb.z), fgelu(a[3] + bb.w));
          *(uint2*)(o0 + idx) = pk;
        }
      }
    }
  }
}

// ================= GEMM 128x256, BK=64, 8 waves, m201-style 2-phase =================
// Per-wave tile 64x64 (wy 0..1 rows, wx 0..3 cols), acc[4][4].
// B rows quadrant-aligned: nh*128 + wx*32 + ni*16 + l16. A read whole at P1.
// LDS: A dbuf 2x16KB, B dbuf 2x2x16KB = 96 KiB.
// Per tile U: P1 {ldA(8)+ldB0(4) | stage B-h1(U+1)->buf^1 | BAR | lgkm0 |
//   16 MFMA nh0 | BAR}; P2 {ldB1(4) | stage A(U+2)->buf, B-h0(U+2)->buf |
//   BAR | lgkm0 | 16 MFMA nh1}; boundary vmcnt(4) (2 half-tiles in flight),
//   vmcnt(0) at last tile; barrier.
template <int MODE>
__global__ __launch_bounds__(512, 2) void gemm128(
    const ushort_t* __restrict__ A, const ushort_t* __restrict__ BT,
    const float* __restrict__ b0, const float* __restrict__ b1,
    const float* __restrict__ b2, const float* __restrict__ resF,
    const ushort_t* __restrict__ resB,
    float* __restrict__ outF, ushort_t* __restrict__ o0,
    ushort_t* __restrict__ o1, ushort_t* __restrict__ o2,
    int M, int N, int K) {
  __shared__ __align__(16) ushort_t lsA[2][128 * 64];
  __shared__ __align__(16) ushort_t lsB[2][2][128 * 64];
  const int t = threadIdx.x;
  const int lane = t & 63, w = t >> 6;
  const int wy = w >> 2, wx = w & 3;
  const int q8 = lane >> 4, l16 = lane & 15;
  const int c7 = l16 & 7;

  const int nX = gridDim.x;
  const int lin = blockIdx.y * nX + blockIdx.x;
  const int cpx = (nX * gridDim.y) >> 3;   // nwg % 8 == 0 at all call sites
  const int L = (lin & 7) * cpx + (lin >> 3);
  const int n0 = (L % nX) * 256;
  const int m0 = (L / nX) * 128;

  const int srow = lane >> 3;
  const int schk = (lane & 7) ^ srow;
  const ushort_t* Ab = A  + (size_t)(m0 + w * 8 + srow) * K + schk * 8;
  const ushort_t* Bb = BT + (size_t)(n0 + w * 8 + srow) * K + schk * 8;

  auto stageA = [&](int k0, int buf) {
    #pragma unroll
    for (int i = 0; i < 2; ++i)
      gload16(Ab + (size_t)(i * 64) * K + k0, &lsA[buf][(i * 64 + w * 8) * 64]);
  };
  auto stageB = [&](int k0, int buf, int half) {
    #pragma unroll
    for (int i = 0; i < 2; ++i)
      gload16(Bb + (size_t)((half * 2 + i) * 64) * K + k0,
              &lsB[buf][half][(i * 64 + w * 8) * 64]);
  };

  auto ldA = [&](int buf, bf16x8 (&A4)[4][2]) {
    #pragma unroll
    for (int mi = 0; mi < 4; ++mi) {
      const ushort_t* p = &lsA[buf][(wy * 64 + mi * 16 + l16) * 64];
      A4[mi][0] = *(const bf16x8*)(p + ((q8 ^ c7) << 3));
      A4[mi][1] = *(const bf16x8*)(p + (((4 + q8) ^ c7) << 3));
    }
  };
  auto ldB = [&](int buf, int nh, bf16x8 (&B2)[2][2]) {
    #pragma unroll
    for (int ni = 0; ni < 2; ++ni) {
      const ushort_t* p = &lsB[buf][nh][(wx * 32 + ni * 16 + l16) * 64];
      B2[ni][0] = *(const bf16x8*)(p + ((q8 ^ c7) << 3));
      B2[ni][1] = *(const bf16x8*)(p + (((4 + q8) ^ c7) << 3));
    }
  };

  f32x4 acc[4][4] = {};
  auto mfmaH = [&](int nh, bf16x8 (&A4)[4][2], bf16x8 (&B2)[2][2]) {
    #pragma unroll
    for (int mi = 0; mi < 4; ++mi)
      #pragma unroll
      for (int ni = 0; ni < 2; ++ni) {
        f32x4 c = acc[mi][nh * 2 + ni];
        c = __builtin_amdgcn_mfma_f32_16x16x32_bf16(B2[ni][0], A4[mi][0], c, 0, 0, 0);
        c = __builtin_amdgcn_mfma_f32_16x16x32_bf16(B2[ni][1], A4[mi][1], c, 0, 0, 0);
        acc[mi][nh * 2 + ni] = c;
      }
  };

  const int nT = K >> 6;
  // prologue: A(0), B-h0(0), B-h1(0), A(1), B-h0(1)  (nT >= 2)
  stageA(0, 0); stageB(0, 0, 0); stageB(0, 0, 1);
  stageA(64, 1); stageB(64, 1, 0);

  bf16x8 bA[4][2];
  bf16x8 bB0[2][2], bB1[2][2];

  for (int U = 0; U < nT; ++U) {
    const int buf = U & 1;
    if (U == nT - 1) asm volatile("s_waitcnt vmcnt(0)" ::: "memory");
    else             asm volatile("s_waitcnt vmcnt(4)" ::: "memory");
    BARM();
    // ---- P1: nh 0
    ldA(buf, bA);
    ldB(buf, 0, bB0);
    if (U + 1 < nT) stageB((U + 1) << 6, buf ^ 1, 1);
    BARM();
    LGKM0();
    __builtin_amdgcn_s_setprio(1);
    mfmaH(0, bA, bB0);
    __builtin_amdgcn_s_setprio(0);
    BARM();
    // ---- P2: nh 1
    ldB(buf, 1, bB1);
    if (U + 2 < nT) { stageA((U + 2) << 6, buf); stageB((U + 2) << 6, buf, 0); }
    BARM();
    LGKM0();
    __builtin_amdgcn_s_setprio(1);
    mfmaH(1, bA, bB1);
    __builtin_amdgcn_s_setprio(0);
    // boundary vmcnt + barrier at loop top
  }

  // ---- epilogues: acc[mi][nh*2+ni]; m = m0+wy*64+mi*16+l16,
  //                 n = n0+(niG>>1)*128+wx*32+(niG&1)*16+q8*4
  if constexpr (MODE == 5) {
    const int kind = n0 >> 10;                       // block-uniform (BN=256 aligned)
    const float* bp = (kind == 0) ? b0 : (kind == 1) ? b1 : b2;
    ushort_t* dst = (kind == 0) ? o0 : (kind == 1) ? o1 : o2;
    #pragma unroll
    for (int niG = 0; niG < 4; ++niG) {
      int nn = (n0 & 1023) + (niG >> 1) * 128 + wx * 32 + (niG & 1) * 16 + q8 * 4;
      int h = nn >> 6, hd = nn & 63;
      float4 bb = *(const float4*)(bp + nn);
      #pragma unroll
      for (int mi = 0; mi < 4; ++mi) {
        int m = m0 + wy * 64 + mi * 16 + l16;
        int b = m >> 11, s = m & (S_ - 1);
        f32x4 a = acc[mi][niG];
        float v0 = a[0] + bb.x, v1 = a[1] + bb.y, v2 = a[2] + bb.z, v3 = a[3] + bb.w;
        if (kind == 0) { v0 *= FA_SCALE; v1 *= FA_SCALE; v2 *= FA_SCALE; v3 *= FA_SCALE; }
        if (kind == 2) {
          // V stored with per-64 column involution s: 16a+4b+c -> 16b+4a+c so
          // flash's sigma-permuted A-fragments become single contiguous b128s.
          int sp = (s & ~60) | ((s & 48) >> 2) | ((s & 12) << 2);
          size_t base = ((size_t)(b * H_ + h) * HD_ + hd) * S_ + sp;
          dst[base]          = f2bf(v0);
          dst[base + S_]     = f2bf(v1);
          dst[base + 2 * S_] = f2bf(v2);
          dst[base + 3 * S_] = f2bf(v3);
        } else {
          uint2 pk;
          pk.x = pack_bf2(v0, v1);
          pk.y = pack_bf2(v2, v3);
          *(uint2*)(dst + ((size_t)(b * H_ + h) * S_ + s) * HD_ + hd) = pk;
        }
      }
    }
  } else {
    #pragma unroll
    for (int niG = 0; niG < 4; ++niG) {
      int n = n0 + (niG >> 1) * 128 + wx * 32 + (niG & 1) * 16 + q8 * 4;
      float4 bb = *(const float4*)(b0 + n);
      #pragma unroll
      for (int mi = 0; mi < 4; ++mi) {
        int m = m0 + wy * 64 + mi * 16 + l16;
        size_t idx = (size_t)m * N + n;
        f32x4 a = acc[mi][niG];
        if constexpr (MODE == 2) {
          float4 r4 = *(const float4*)(resF + idx);
          uint2 pk;
          pk.x = pack_bf2(r4.x + a[0] + bb.x, r4.y + a[1] + bb.y);
          pk.y = pack_bf2(r4.z + a[2] + bb.z, r4.w + a[3] + bb.w);
          *(uint2*)(o0 + idx) = pk;
        } else if constexpr (MODE == 4) {
          ushort4 r4 = *(const ushort4*)(resB + idx);
          float4 o4;
          o4.x = bf2f(r4.x) + a[0] + bb.x;
          o4.y = bf2f(r4.y) + a[1] + bb.y;
          o4.z = bf2f(r4.z) + a[2] + bb.z;
          o4.w = bf2f(r4.w) + a[3] + bb.w;
          *(float4*)(outF + idx) = o4;
        } else {  // MODE 3
          uint2 pk;
          pk.x = pack_bf2(fgelu(a[0] + bb.x), fgelu(a[1] + bb.y));
          pk.y = pack_bf2(fgelu(a[2] + bb.z), fgelu(a[3] + bb.w));
          *(uint2*)(o0 + idx) = pk;
        }
      }
    }
  }
}

// ---------------- flash attention v5 (register-resident P, 32 KB LDS) ----------------
// Qt (pre-scaled), Kt: bf16 [BH][S][HD]; Vt: bf16 [BH][HD][S-perm]; Ao: bf16 [B,S,H,HD]
// Vt's S dim carries the per-64 involution s:16a+4b+c -> 16b+4a+c (applied at the
// QKV V-store), so each PV A-fragment is ONE contiguous ds_read_b128 at chunk
// (2*q8+kc)^c7 — the same conflict-free class as the K reads (was 4x b64, 4-way
// conflicted, 8.4M conflict cycles).
__global__ __launch_bounds__(256) void flash_attn(
    const ushort_t* __restrict__ Qt, const ushort_t* __restrict__ Kt,
    const ushort_t* __restrict__ Vt, ushort_t* __restrict__ Ao) {
  __shared__ __align__(16) ushort_t ks[2][64 * 64];
  __shared__ __align__(16) ushort_t vs[2][64 * 64];
  const int t = threadIdx.x;
  const int lane = t & 63, w = t >> 6;
  const int q8 = lane >> 4, l16 = lane & 15;
  const int bh = blockIdx.x, q0 = blockIdx.y * 128;
  const int c7 = l16 & 7;
  const int koff0 = ((q8)     ^ c7) * 8;
  const int koff1 = ((4 + q8) ^ c7) * 8;
  const int voff0 = ((2 * q8)     ^ c7) * 8;
  const int voff1 = ((2 * q8 + 1) ^ c7) * 8;

  bf16x8 bq[2][2];
  #pragma unroll
  for (int u = 0; u < 2; ++u)
    #pragma unroll
    for (int kc = 0; kc < 2; ++kc) {
      int row = q0 + w * 32 + u * 16 + l16;
      bq[u][kc] = *(const bf16x8*)(Qt + ((size_t)bh * S_ + row) * HD_ + kc * 32 + q8 * 8);
    }

  const ushort_t* Kg = Kt + (size_t)bh * S_ * HD_;
  const ushort_t* Vg = Vt + (size_t)bh * HD_ * S_;

  #pragma unroll
  for (int i = 0; i < 2; ++i) {
    int slot = i * 256 + t;
    int row = slot >> 3, gch = (slot & 7) ^ (row & 7);
    gload16(Kg + row * HD_ + gch * 8,        ks[0] + (i * 256 + w * 64) * 8);
    gload16(Vg + (size_t)row * S_ + gch * 8, vs[0] + (i * 256 + w * 64) * 8);
  }

  bf16x8 kone;
  #pragma unroll
  for (int i = 0; i < 8; ++i) kone[i] = (__bf16)1.0f;

  f32x4 accO[2][4] = {};
  f32x4 accL[2] = {};

  for (int it = 0; it < S_ / 64; ++it) {
    __syncthreads();
    const int cur = it & 1;
    if (it + 1 < S_ / 64) {
      const ushort_t* Kn = Kg + (size_t)(it + 1) * 64 * HD_;
      const ushort_t* Vn = Vg + (it + 1) * 64;
      #pragma unroll
      for (int i = 0; i < 2; ++i) {
        int slot = i * 256 + t;
        int row = slot >> 3, gch = (slot & 7) ^ (row & 7);
        gload16(Kn + row * HD_ + gch * 8,        ks[cur ^ 1] + (i * 256 + w * 64) * 8);
        gload16(Vn + (size_t)row * S_ + gch * 8, vs[cur ^ 1] + (i * 256 + w * 64) * 8);
      }
    }
    const ushort_t* kbuf = ks[cur];
    const ushort_t* vbuf = vs[cur];

    // ---- S^T = K . Q^T ----
    f32x4 st[2][4];
    #pragma unroll
    for (int ni = 0; ni < 4; ++ni) {
      const ushort_t* kr = kbuf + (ni * 16 + l16) * 64;
      bf16x8 ak0 = *(const bf16x8*)(kr + koff0);
      bf16x8 ak1 = *(const bf16x8*)(kr + koff1);
      #pragma unroll
      for (int u = 0; u < 2; ++u) {
        f32x4 z = {0.f, 0.f, 0.f, 0.f};
        z = __builtin_amdgcn_mfma_f32_16x16x32_bf16(ak0, bq[u][0], z, 0, 0, 0);
        z = __builtin_amdgcn_mfma_f32_16x16x32_bf16(ak1, bq[u][1], z, 0, 0, 0);
        st[u][ni] = z;
      }
    }
    // ---- exp2 + pack; PV B-operand = own registers (sigma-permuted kv order) ----
    bf16x8 bp[2][2];
    #pragma unroll
    for (int u = 0; u < 2; ++u) {
      uint2 pk[4];
      #pragma unroll
      for (int ni = 0; ni < 4; ++ni) {
        pk[ni].x = pack_bf2(fexp2(st[u][ni][0]), fexp2(st[u][ni][1]));
        pk[ni].y = pack_bf2(fexp2(st[u][ni][2]), fexp2(st[u][ni][3]));
      }
      u32x4 d0 = {pk[0].x, pk[0].y, pk[1].x, pk[1].y};
      u32x4 d1 = {pk[2].x, pk[2].y, pk[3].x, pk[3].y};
      bp[u][0] = __builtin_bit_cast(bf16x8, d0);
      bp[u][1] = __builtin_bit_cast(bf16x8, d1);
    }
    // ---- denominator on MFMA pipe (sum over kv is permutation-invariant) ----
    #pragma unroll
    for (int u = 0; u < 2; ++u) {
      accL[u] = __builtin_amdgcn_mfma_f32_16x16x32_bf16(kone, bp[u][0], accL[u], 0, 0, 0);
      accL[u] = __builtin_amdgcn_mfma_f32_16x16x32_bf16(kone, bp[u][1], accL[u], 0, 0, 0);
    }
    // ---- O^T += V^T . P^T ; A-fragments are contiguous b128s (store-side perm) ----
    #pragma unroll
    for (int ni = 0; ni < 4; ++ni) {
      const ushort_t* vr = vbuf + (ni * 16 + l16) * 64;
      bf16x8 av0 = *(const bf16x8*)(vr + voff0);
      bf16x8 av1 = *(const bf16x8*)(vr + voff1);
      #pragma unroll
      for (int u = 0; u < 2; ++u) {
        accO[u][ni] = __builtin_amdgcn_mfma_f32_16x16x32_bf16(av0, bp[u][0], accO[u][ni], 0, 0, 0);
        accO[u][ni] = __builtin_amdgcn_mfma_f32_16x16x32_bf16(av1, bp[u][1], accO[u][ni], 0, 0, 0);
      }
    }
  }

  const int b = bh >> 4, h = bh & 15;
  #pragma unroll
  for (int u = 0; u < 2; ++u) {
    float inv = 1.0f / accL[u][0];
    int q = q0 + w * 32 + u * 16 + l16;
    #pragma unroll
    for (int ni = 0; ni < 4; ++ni) {
      uint2 pk;
      pk.x = pack_bf2(accO[u][ni][0] * inv, accO[u][ni][1] * inv);
      pk.y = pack_bf2(accO[u][ni][2] * inv, accO[u][ni][3] * inv);
      *(uint2*)(Ao + (((size_t)b * S_ + q) * H_ + h) * HD_ + ni * 16 + q8 * 4) = pk;
    }
  }
}

extern "C" void kernel_launch(void* const* d_in, const int* in_sizes, int n_in,
                              void* d_out, int out_size, void* d_ws, size_t ws_size,
                              hipStream_t stream) {
  const float* x    = (const float*)d_in[0];
  const float* Wq   = (const float*)d_in[1];
  const float* bq   = (const float*)d_in[2];
  const float* Wk   = (const float*)d_in[3];
  const float* bk   = (const float*)d_in[4];
  const float* Wv   = (const float*)d_in[5];
  const float* bv   = (const float*)d_in[6];
  const float* Wo   = (const float*)d_in[7];
  const float* bo   = (const float*)d_in[8];
  const float* ln1g = (const float*)d_in[9];
  const float* ln1b = (const float*)d_in[10];
  const float* ln2g = (const float*)d_in[11];
  const float* ln2b = (const float*)d_in[12];
  const float* W1   = (const float*)d_in[13];
  const float* b1   = (const float*)d_in[14];
  const float* W2   = (const float*)d_in[15];
  const float* b2   = (const float*)d_in[16];
  float* out = (float*)d_out;

  char* ws = (char*)d_ws;
  ushort_t* WqT = (ushort_t*)(ws + (size_t)(0)  * (1 << 20));  // 2 MB  } contiguous
  ushort_t* WkT = (ushort_t*)(ws + (size_t)(2)  * (1 << 20));  // 2 MB  } [3072][1024]
  ushort_t* WvT = (ushort_t*)(ws + (size_t)(4)  * (1 << 20));  // 2 MB  } fused QKV
  ushort_t* WoT = (ushort_t*)(ws + (size_t)(6)  * (1 << 20));  // 2 MB
  ushort_t* W1T = (ushort_t*)(ws + (size_t)(8)  * (1 << 20));  // 8 MB  [DF][D]
  ushort_t* W2T = (ushort_t*)(ws + (size_t)(16) * (1 << 20));  // 8 MB  [D][DF]
  ushort_t* xn  = (ushort_t*)(ws + (size_t)(24) * (1 << 20));  // 16 MB [M][D]
  ushort_t* qT  = (ushort_t*)(ws + (size_t)(40) * (1 << 20));  // 16 MB [BH][S][HD]
  ushort_t* kT  = (ushort_t*)(ws + (size_t)(56) * (1 << 20));  // 16 MB
  ushort_t* vT  = (ushort_t*)(ws + (size_t)(72) * (1 << 20));  // 16 MB [BH][HD][S-perm]
  ushort_t* ao  = (ushort_t*)(ws + (size_t)(88) * (1 << 20));  // 16 MB [B,S,H,HD]
  ushort_t* x2b = (ushort_t*)(ws + (size_t)(104)* (1 << 20));  // 16 MB [M][D] bf16 residual
  ushort_t* hb  = (ushort_t*)(ws + (size_t)(136)* (1 << 20));  // 64 MB [M][DF]

  dim3 blk(256), blk5(512);
  TP4 tp;
  tp.src[0] = Wq; tp.src[1] = Wk; tp.src[2] = Wv; tp.src[3] = Wo;
  tp.dst[0] = WqT; tp.dst[1] = WkT; tp.dst[2] = WvT; tp.dst[3] = WoT;
  transpose_cvt4<<<dim3(D_/32, D_/32, 4), blk, 0, stream>>>(tp);
  transpose_cvt<<<dim3(DF_/32, D_/32),  blk, 0, stream>>>(W1, W1T, D_, DF_);
  transpose_cvt<<<dim3(D_/32,  DF_/32), blk, 0, stream>>>(W2, W2T, DF_, D_);

  // LN1 (fp32 in)
  ln_kernel<0><<<M_, blk, 0, stream>>>(x, ln1g, ln1b, xn);
  // fused QKV projection: 12x64 = 768 blocks = 3 exact block-waves
  gemm128<5><<<dim3(3072/256, M_/128), blk5, 0, stream>>>(
      xn, WqT, bq, bk, bv, nullptr, nullptr, nullptr, qT, kT, vT, M_, 3072, D_);
  // attention
  flash_attn<<<dim3(B_*H_, S_/128), blk, 0, stream>>>(qT, kT, vT, ao);
  // output projection + residual -> bf16 x2: 4x64 = 256 blocks = 1/CU
  gemm128<2><<<dim3(D_/256, M_/128), blk5, 0, stream>>>(
      ao, WoT, bo, nullptr, nullptr, x, nullptr, nullptr, x2b, nullptr, nullptr, M_, D_, D_);
  // LN2 (bf16 in)
  ln_kernel<1><<<M_, blk, 0, stream>>>(x2b, ln2g, ln2b, xn);
  // FFN1: 16x32 = 512 blocks = 2 exact block-waves (256x256 tiles)
  gemm256<3><<<dim3(DF_/256, M_/256), blk5, 0, stream>>>(
      xn, W1T, b1, nullptr, nullptr, nullptr, nullptr, nullptr, hb, nullptr, nullptr, M_, DF_, D_);
  // FFN2: 4x64 = 256 blocks = 1/CU, K=4096
  gemm128<4><<<dim3(D_/256, M_/128), blk5, 0, stream>>>(
      hb, W2T, b2, nullptr, nullptr, nullptr, x2b, out, nullptr, nullptr, nullptr, M_, D_, DF_);
}